// Round 8
// baseline (624.236 us; speedup 1.0000x reference)
//
#include <hip/hip_runtime.h>
#include <math.h>

#define NB 4
#define NN 1024
#define ND 128
#define NUM_IN 64
#define F_EPS 1e-8f
#define BT_SCALE 1.8477590650225735f      // sqrt(2+sqrt(2))
#define INV_SQRT_D 0.08838834764831844f   // 1/sqrt(128)
#define BASELINE (1.0f/1025.0f)
#define OUT_STRIDE 256
#define A_OFF 1048576                     // floats: NB*NN*OUT_STRIDE

// swizzled LDS index for a 1024-vector accessed as v[8*lane + j]
#define SWZ(c) ((((c) & 7) << 7) | ((c) >> 3))

__device__ __forceinline__ float buntanh_f(float x) {
    return BT_SCALE * (0.5f * x + 0.5f * tanhf(x));
}
__device__ __forceinline__ float wave_sum(float v) {
    #pragma unroll
    for (int off = 32; off > 0; off >>= 1) v += __shfl_xor(v, off, 64);
    return v;
}
__device__ __forceinline__ float bflo(unsigned u) { return __uint_as_float(u << 16); }
__device__ __forceinline__ float bfhi(unsigned u) { return __uint_as_float(u & 0xffff0000u); }
__device__ __forceinline__ unsigned bf_rne(float f) {
    unsigned x = __float_as_uint(f);
    return (x + 0x7fffu + ((x >> 16) & 1u)) >> 16;
}
__device__ __forceinline__ unsigned bf_pack(float lo, float hi) {
    return bf_rne(lo) | (bf_rne(hi) << 16);
}

typedef float f32x4 __attribute__((ext_vector_type(4)));
__device__ __forceinline__ float4 ntload4(const float4* p) {
    f32x4 v = __builtin_nontemporal_load((const f32x4*)p);
    return make_float4(v.x, v.y, v.z, v.w);
}

// ---------- piggyback: one node's prediction = buntanh(state . w1) ----------
__device__ __forceinline__ void pred_node(
    const int node, const float* __restrict__ state,
    const float* __restrict__ w1, float* __restrict__ dout)
{
    __shared__ float4 pred_red[8][32];
    const int t = threadIdx.x;
    const int g = t >> 5, m = t & 31;
    const float4* w4 = (const float4*)(w1 + ((size_t)node << 14));
    const float* srow = state + ((size_t)node << 7);
    float4 acc = make_float4(0.f, 0.f, 0.f, 0.f);
    #pragma unroll
    for (int h = 0; h < 2; ++h) {
        float4 wv[8];
        #pragma unroll
        for (int i = 0; i < 8; ++i) wv[i] = ntload4(&w4[(h*8 + i)*256 + t]);
        #pragma unroll
        for (int i = 0; i < 8; ++i) {
            const float s = srow[(h*8 + i)*8 + g];
            acc.x += s*wv[i].x; acc.y += s*wv[i].y;
            acc.z += s*wv[i].z; acc.w += s*wv[i].w;
        }
    }
    pred_red[g][m] = acc;
    __syncthreads();
    if (t < 32) {
        float4 o = pred_red[0][t];
        #pragma unroll
        for (int gg = 1; gg < 8; ++gg) {
            const float4 r = pred_red[gg][t];
            o.x += r.x; o.y += r.y; o.z += r.z; o.w += r.w;
        }
        o.x = buntanh_f(o.x); o.y = buntanh_f(o.y);
        o.z = buntanh_f(o.z); o.w = buntanh_f(o.w);
        *(float4*)(dout + (size_t)node * OUT_STRIDE + ND + 4*t) = o;
    }
}

// ---------- K1: per-node matvecs (w2,w3) -> K, Q ----------
__global__ __launch_bounds__(256, 8) void qk_kernel(
    const float* __restrict__ state,
    const float* __restrict__ w2,
    const float* __restrict__ w3,
    float* __restrict__ Qg,
    float* __restrict__ Kg)
{
    const int blk = blockIdx.x;
    const int node = ((blk & 7) << 9) | (blk >> 3);   // XCD-chunked

    __shared__ float s_state[ND];
    __shared__ float4 red[2][8][32];

    const int t = threadIdx.x;
    if (t < 32) ((float4*)s_state)[t] =
        ((const float4*)(state + ((size_t)node << 7)))[t];
    __syncthreads();

    const int g = t >> 5, m = t & 31;

    auto do_mat = [&](const float* wbase, int q) {
        const float4* w4 = (const float4*)(wbase + ((size_t)node << 14));
        float4 wv[8];
        float4 acc = make_float4(0.f, 0.f, 0.f, 0.f);
        #pragma unroll
        for (int i = 0; i < 8; ++i) wv[i] = ntload4(&w4[i*256 + t]);
        #pragma unroll
        for (int i = 0; i < 8; ++i) {
            const float s = s_state[i*8 + g];
            acc.x += s*wv[i].x; acc.y += s*wv[i].y;
            acc.z += s*wv[i].z; acc.w += s*wv[i].w;
        }
        #pragma unroll
        for (int i = 0; i < 8; ++i) wv[i] = ntload4(&w4[(8+i)*256 + t]);
        #pragma unroll
        for (int i = 0; i < 8; ++i) {
            const float s = s_state[(8+i)*8 + g];
            acc.x += s*wv[i].x; acc.y += s*wv[i].y;
            acc.z += s*wv[i].z; acc.w += s*wv[i].w;
        }
        red[q][g][m] = acc;
    };
    do_mat(w2, 0);      // -> K
    do_mat(w3, 1);      // -> Q
    __syncthreads();

    if (t < 64) {
        const int q = t >> 5, mm = t & 31;
        float4 o = red[q][0][mm];
        #pragma unroll
        for (int gg = 1; gg < 8; ++gg) {
            const float4 r = red[q][gg][mm];
            o.x += r.x; o.y += r.y; o.z += r.z; o.w += r.w;
        }
        o.x = buntanh_f(o.x); o.y = buntanh_f(o.y);
        o.z = buntanh_f(o.z); o.w = buntanh_f(o.w);
        float* base = (q == 0) ? Kg : Qg;
        *(float4*)(base + ((size_t)node << 7) + 4*mm) = o;
    }
}

// ---------- K2: raw_A = Q K^T * inv_sqrt_d -> raw (bf16); ssq atomics ----------
// grid: 4096 main + 1536 pred
__global__ __launch_bounds__(256) void qk2_kernel(
    const float* __restrict__ Qg, const float* __restrict__ Kg,
    unsigned* __restrict__ rawbf, float* __restrict__ reds,
    const float* __restrict__ state, const float* __restrict__ w1,
    float* __restrict__ dout, int predBase)
{
    if (blockIdx.x >= 4096) {
        pred_node(predBase + (int)blockIdx.x - 4096, state, w1, dout);
        return;
    }
    const int b = blockIdx.x >> 10;
    const int tile = blockIdx.x & 1023;
    const int tr = tile >> 5, tc = tile & 31;

    __shared__ float Qs[32][132];
    __shared__ float Ks[32][136];
    __shared__ float wr4[4];

    const int t = threadIdx.x;
    for (int i = t; i < 1024; i += 256) {
        const int r = i >> 5, q = i & 31;
        *(float4*)&Qs[r][q*4] = *(const float4*)(Qg + (((size_t)(b*NN + tr*32 + r)) << 7) + q*4);
        *(float4*)&Ks[r][q*4] = *(const float4*)(Kg + (((size_t)(b*NN + tc*32 + r)) << 7) + q*4);
    }
    __syncthreads();

    const int ty = t >> 4;
    const int tx = t & 15;
    float a00=0.f, a01=0.f, a10=0.f, a11=0.f;
    #pragma unroll
    for (int dq = 0; dq < 32; ++dq) {
        const float4 q0 = *(const float4*)&Qs[ty][dq*4];
        const float4 q1 = *(const float4*)&Qs[ty+16][dq*4];
        const float4 k0 = *(const float4*)&Ks[2*tx][dq*4];
        const float4 k1 = *(const float4*)&Ks[2*tx+1][dq*4];
        a00 += q0.x*k0.x + q0.y*k0.y + q0.z*k0.z + q0.w*k0.w;
        a01 += q0.x*k1.x + q0.y*k1.y + q0.z*k1.z + q0.w*k1.w;
        a10 += q1.x*k0.x + q1.y*k0.y + q1.z*k0.z + q1.w*k0.w;
        a11 += q1.x*k1.x + q1.y*k1.y + q1.z*k1.z + q1.w*k1.w;
    }
    a00 *= INV_SQRT_D; a01 *= INV_SQRT_D; a10 *= INV_SQRT_D; a11 *= INV_SQRT_D;

    unsigned* r0p = rawbf + (((size_t)(b*NN + tr*32 + ty)) << 9) + tc*16;
    unsigned* r1p = rawbf + (((size_t)(b*NN + tr*32 + ty + 16)) << 9) + tc*16;
    r0p[tx] = bf_pack(a00, a01);
    r1p[tx] = bf_pack(a10, a11);

    float ssq = a00*a00 + a01*a01 + a10*a10 + a11*a11;
    ssq = wave_sum(ssq);
    if ((t & 63) == 0) wr4[t >> 6] = ssq;
    __syncthreads();
    if (t == 0) atomicAdd(&reds[b], wr4[0]+wr4[1]+wr4[2]+wr4[3]);
}

// ---------- K3: EMA+mask+eps; write M0, M0^T (bf16); rowsum atomics ----------
// grid: 1024 main + 768 pred
__global__ __launch_bounds__(256) void emaT_kernel(
    const unsigned* __restrict__ rawbf, const float* __restrict__ A_ema,
    const float* __restrict__ reds,
    unsigned* __restrict__ M0, unsigned* __restrict__ M0T,
    float* __restrict__ SR,
    const float* __restrict__ state, const float* __restrict__ w1,
    float* __restrict__ dout, int predBase)
{
    if (blockIdx.x >= 1024) {
        pred_node(predBase + (int)blockIdx.x - 1024, state, w1, dout);
        return;
    }
    const int b = blockIdx.x >> 8;
    const int tile = blockIdx.x & 255;
    const int tr = tile >> 4, tc = tile & 15;
    const int R0 = tr << 6, C0 = tc << 6;

    __shared__ float st[64][65];
    __shared__ float s_part[64][5];

    const int t = threadIdx.x;
    const int r = t >> 2, q = t & 3;
    const int row = R0 + r;
    const float scale = rsqrtf(reds[b] * (1.0f/1048576.0f) + F_EPS);

    const unsigned* rawrow = rawbf + (((size_t)(b*NN + row)) << 9) + tc*8*4;
    const uint4 u0 = ((const uint4*)rawrow)[q*2];
    const uint4 u1 = ((const uint4*)rawrow)[q*2 + 1];
    float rv[16];
    rv[0]=bflo(u0.x); rv[1]=bfhi(u0.x); rv[2]=bflo(u0.y); rv[3]=bfhi(u0.y);
    rv[4]=bflo(u0.z); rv[5]=bfhi(u0.z); rv[6]=bflo(u0.w); rv[7]=bfhi(u0.w);
    rv[8]=bflo(u1.x); rv[9]=bfhi(u1.x); rv[10]=bflo(u1.y); rv[11]=bfhi(u1.y);
    rv[12]=bflo(u1.z); rv[13]=bfhi(u1.z); rv[14]=bflo(u1.w); rv[15]=bfhi(u1.w);

    const float* emarow = A_ema + (((size_t)(b*NN + row)) << 10) + C0 + q*16;
    float s = 0.f;
    #pragma unroll
    for (int j = 0; j < 4; ++j) {
        const float4 e = ((const float4*)emarow)[j];
        float ev[4] = {e.x, e.y, e.z, e.w};
        #pragma unroll
        for (int k = 0; k < 4; ++k) {
            const int e_idx = j*4 + k;
            const int c = C0 + q*16 + e_idx;
            float em = ev[k];
            if (row == NUM_IN && c < NUM_IN) em += 3.0f / NUM_IN;
            float v = em * 0.99f + rv[e_idx] * scale * 0.01f;
            if (row < NUM_IN) v = 0.f;
            v = fmaxf(v, 0.f) + F_EPS;
            rv[e_idx] = v;
            st[r][q*16 + e_idx] = v;
            s += v;
        }
    }
    s_part[r][q] = s;

    unsigned* m0row = M0 + (((size_t)(b*NN + row)) << 9) + tc*8*4;
    uint4 o0, o1;
    o0.x = bf_pack(rv[0],rv[1]);  o0.y = bf_pack(rv[2],rv[3]);
    o0.z = bf_pack(rv[4],rv[5]);  o0.w = bf_pack(rv[6],rv[7]);
    o1.x = bf_pack(rv[8],rv[9]);  o1.y = bf_pack(rv[10],rv[11]);
    o1.z = bf_pack(rv[12],rv[13]); o1.w = bf_pack(rv[14],rv[15]);
    ((uint4*)m0row)[q*2]     = o0;
    ((uint4*)m0row)[q*2 + 1] = o1;
    __syncthreads();

    if (t < 64) {
        const float rs = s_part[t][0] + s_part[t][1] + s_part[t][2] + s_part[t][3];
        atomicAdd(&SR[b*NN + R0 + t], rs);
    }

    const int cT = t >> 2;
    float tv[16];
    #pragma unroll
    for (int k = 0; k < 16; ++k) tv[k] = st[q*16 + k][cT];
    uint4 w0, w1v;
    w0.x = bf_pack(tv[0],tv[1]);  w0.y = bf_pack(tv[2],tv[3]);
    w0.z = bf_pack(tv[4],tv[5]);  w0.w = bf_pack(tv[6],tv[7]);
    w1v.x = bf_pack(tv[8],tv[9]);  w1v.y = bf_pack(tv[10],tv[11]);
    w1v.z = bf_pack(tv[12],tv[13]); w1v.w = bf_pack(tv[14],tv[15]);
    unsigned* mtrow = M0T + (((size_t)(b*NN + C0 + cT)) << 9) + tr*8*4;
    ((uint4*)mtrow)[q*2]     = w0;
    ((uint4*)mtrow)[q*2 + 1] = w1v;
}

// ---------- K4: fused Sinkhorn call (15 matvecs, device-wide barriers) ----------
// cooperative: 256 blocks x 1024 threads (1 block/CU). wave w handles row rbase+w.
// phase even: y=cbuf, A=Mcol; phase odd: y=rbuf, A=Mrow. All y in INVERTED form.
__global__ __launch_bounds__(1024) void sink_coop(
    const unsigned* __restrict__ Mrow,   // M0 (or A1)
    const unsigned* __restrict__ Mcol,   // M0T (or A1T)
    const float* __restrict__ s0,        // initial rowsums (inverted on load)
    float* __restrict__ cbuf, float* __restrict__ rbuf,
    unsigned* __restrict__ cnt)          // 16 zeroed counters
{
    __shared__ float xs[NN];
    const int blk = blockIdx.x;
    const int b = blk >> 6;
    const int rbase = (blk & 63) << 4;
    const int t = threadIdx.x;
    const int w = t >> 6, l = t & 63;
    const int row = rbase + w;

    for (int p = 0; p < 15; ++p) {
        const bool even = ((p & 1) == 0);
        const unsigned* A = even ? Mcol : Mrow;
        const float* xin = (p == 0) ? s0 : (even ? rbuf : cbuf);
        float* yout = even ? cbuf : rbuf;

        // stage x into LDS (agent-coherent load), SWZ layout
        float xv = __hip_atomic_load(&xin[(b << 10) + t], __ATOMIC_RELAXED,
                                     __HIP_MEMORY_SCOPE_AGENT);
        if (p == 0) xv = 1.0f / xv;
        xs[SWZ(t)] = xv;
        __syncthreads();

        const unsigned* rp = A + (((size_t)((b << 10) + row)) << 9);
        const uint4 v0 = ((const uint4*)rp)[l];
        const uint4 v1 = ((const uint4*)rp)[64 + l];
        const float* xA = &xs[l];          // xA[j<<7] = col 8l+j
        const float* xB = &xs[64 + l];     // xB[j<<7] = col 512+8l+j
        float a = bflo(v0.x)*xA[0<<7] + bfhi(v0.x)*xA[1<<7]
                + bflo(v0.y)*xA[2<<7] + bfhi(v0.y)*xA[3<<7]
                + bflo(v0.z)*xA[4<<7] + bfhi(v0.z)*xA[5<<7]
                + bflo(v0.w)*xA[6<<7] + bfhi(v0.w)*xA[7<<7]
                + bflo(v1.x)*xB[0<<7] + bfhi(v1.x)*xB[1<<7]
                + bflo(v1.y)*xB[2<<7] + bfhi(v1.y)*xB[3<<7]
                + bflo(v1.z)*xB[4<<7] + bfhi(v1.z)*xB[5<<7]
                + bflo(v1.w)*xB[6<<7] + bfhi(v1.w)*xB[7<<7];
        a = wave_sum(a);
        if (l == 0)
            __hip_atomic_store(&yout[(b << 10) + row], 1.0f / a,
                               __ATOMIC_RELAXED, __HIP_MEMORY_SCOPE_AGENT);
        __syncthreads();

        if (p < 14) {       // device-wide barrier between phases
            if (t == 0) {
                __hip_atomic_fetch_add(&cnt[p], 1u, __ATOMIC_ACQ_REL,
                                       __HIP_MEMORY_SCOPE_AGENT);
                while (__hip_atomic_load(&cnt[p], __ATOMIC_ACQUIRE,
                                         __HIP_MEMORY_SCOPE_AGENT) < 256u)
                    __builtin_amdgcn_s_sleep(2);
            }
            __syncthreads();
        }
    }
}

// ---------- K5: threshold+eps -> A1, A1^T (bf16); rowsums -> SR2 ----------
// grid 256 main + 768 pred
__global__ __launch_bounds__(256) void thresh_kernel(
    const unsigned* __restrict__ M0, const unsigned* __restrict__ M0T,
    const float* __restrict__ r8, const float* __restrict__ c8,
    unsigned* __restrict__ A1, unsigned* __restrict__ A1T,
    float* __restrict__ SR2,
    const float* __restrict__ state, const float* __restrict__ w1,
    float* __restrict__ dout, int predBase)
{
    if (blockIdx.x >= 256) {
        pred_node(predBase + (int)blockIdx.x - 256, state, w1, dout);
        return;
    }
    const int t = threadIdx.x;
    const int b = blockIdx.x >> 6;
    const int g0 = (blockIdx.x & 63) << 4;
    const int w = t >> 6, l = t & 63;
    const bool doA1 = (w < 2);
    const int wr = doA1 ? w : (w - 2);
    const unsigned* src = doA1 ? M0 : M0T;
    unsigned*       dst = doA1 ? A1 : A1T;
    const float* rowS = doA1 ? r8 : c8;
    const float* colS = doA1 ? c8 : r8;

    const float4* cb = (const float4*)(colS + (b << 10));
    const float4 c0 = cb[2*l], c1 = cb[2*l+1], c2 = cb[128+2*l], c3 = cb[129+2*l];
    const float cm[16] = {c0.x,c0.y,c0.z,c0.w, c1.x,c1.y,c1.z,c1.w,
                          c2.x,c2.y,c2.z,c2.w, c3.x,c3.y,c3.z,c3.w};

    for (int rr = 0; rr < 8; ++rr) {
        const int row = g0 + wr*8 + rr;
        const float ri = rowS[(b << 10) + row];
        const unsigned* rp = src + (((size_t)(b*NN + row)) << 9);
        const uint4 v0 = ((const uint4*)rp)[l];
        const uint4 v1 = ((const uint4*)rp)[64 + l];
        float e[16];
        e[0]=bflo(v0.x); e[1]=bfhi(v0.x); e[2]=bflo(v0.y); e[3]=bfhi(v0.y);
        e[4]=bflo(v0.z); e[5]=bfhi(v0.z); e[6]=bflo(v0.w); e[7]=bfhi(v0.w);
        e[8]=bflo(v1.x); e[9]=bfhi(v1.x); e[10]=bflo(v1.y); e[11]=bfhi(v1.y);
        e[12]=bflo(v1.z); e[13]=bfhi(v1.z); e[14]=bflo(v1.w); e[15]=bfhi(v1.w);
        float s = 0.f;
        #pragma unroll
        for (int j = 0; j < 16; ++j) {
            const float d = e[j] * ri * cm[j];
            e[j] = (d > BASELINE ? d : 0.f) + F_EPS;
            s += e[j];
        }
        uint4 o0, o1;
        o0.x = bf_pack(e[0],e[1]);  o0.y = bf_pack(e[2],e[3]);
        o0.z = bf_pack(e[4],e[5]);  o0.w = bf_pack(e[6],e[7]);
        o1.x = bf_pack(e[8],e[9]);  o1.y = bf_pack(e[10],e[11]);
        o1.z = bf_pack(e[12],e[13]); o1.w = bf_pack(e[14],e[15]);
        unsigned* op = dst + (((size_t)(b*NN + row)) << 9);
        ((uint4*)op)[l] = o0;
        ((uint4*)op)[64 + l] = o1;
        if (doA1) {
            s = wave_sum(s);
            if (l == 0) SR2[b*NN + row] = s;
        }
    }
}

// ---------- K6: final scale + mask -> A (fp32); variance partials ----------
// grid 256 main + 512 pred
__global__ __launch_bounds__(256) void fin_kernel(
    const unsigned* __restrict__ A1, const float* __restrict__ r8,
    const float* __restrict__ c8, float* __restrict__ reds,
    float* __restrict__ dout,
    const float* __restrict__ state, const float* __restrict__ w1,
    int predBase)
{
    if (blockIdx.x >= 256) {
        pred_node(predBase + (int)blockIdx.x - 256, state, w1, dout);
        return;
    }
    __shared__ float wred[8];
    const int t = threadIdx.x;
    const int b = blockIdx.x >> 6;
    const int g0 = (blockIdx.x & 63) << 4;
    const int w = t >> 6, l = t & 63;

    const float4* cb = (const float4*)(c8 + (b << 10));
    const float4 c0 = cb[2*l], c1 = cb[2*l+1], c2 = cb[128+2*l], c3 = cb[129+2*l];
    const float cm[16] = {c0.x,c0.y,c0.z,c0.w, c1.x,c1.y,c1.z,c1.w,
                          c2.x,c2.y,c2.z,c2.w, c3.x,c3.y,c3.z,c3.w};

    float s1 = 0.f, s2 = 0.f;
    for (int rr = 0; rr < 4; ++rr) {
        const int row = g0 + w*4 + rr;
        float* Arow = dout + A_OFF + (((size_t)(b*NN + row)) << 10);
        if (row < NUM_IN) {
            const float4 z = make_float4(0.f,0.f,0.f,0.f);
            ((float4*)Arow)[2*l] = z;       ((float4*)Arow)[2*l+1] = z;
            ((float4*)Arow)[128+2*l] = z;   ((float4*)Arow)[129+2*l] = z;
        } else {
            const float ri = r8[(b << 10) + row];
            const unsigned* rp = A1 + (((size_t)(b*NN + row)) << 9);
            const uint4 v0 = ((const uint4*)rp)[l];
            const uint4 v1 = ((const uint4*)rp)[64 + l];
            float e[16];
            e[0]=bflo(v0.x); e[1]=bfhi(v0.x); e[2]=bflo(v0.y); e[3]=bfhi(v0.y);
            e[4]=bflo(v0.z); e[5]=bfhi(v0.z); e[6]=bflo(v0.w); e[7]=bfhi(v0.w);
            e[8]=bflo(v1.x); e[9]=bfhi(v1.x); e[10]=bflo(v1.y); e[11]=bfhi(v1.y);
            e[12]=bflo(v1.z); e[13]=bfhi(v1.z); e[14]=bflo(v1.w); e[15]=bfhi(v1.w);
            #pragma unroll
            for (int j = 0; j < 16; ++j) {
                e[j] = e[j] * ri * cm[j];
                s1 += e[j]; s2 += e[j]*e[j];
            }
            ((float4*)Arow)[2*l]     = make_float4(e[0],e[1],e[2],e[3]);
            ((float4*)Arow)[2*l+1]   = make_float4(e[4],e[5],e[6],e[7]);
            ((float4*)Arow)[128+2*l] = make_float4(e[8],e[9],e[10],e[11]);
            ((float4*)Arow)[129+2*l] = make_float4(e[12],e[13],e[14],e[15]);
        }
    }
    s1 = wave_sum(s1); s2 = wave_sum(s2);
    if (l == 0) { wred[w] = s1; wred[4 + w] = s2; }
    __syncthreads();
    if (t == 0) {
        atomicAdd(&reds[4 + b], wred[0]+wred[1]+wred[2]+wred[3]);
        atomicAdd(&reds[8 + b], wred[4]+wred[5]+wred[6]+wred[7]);
    }
}

// ---------- K7: V = output + relu(0.02 - var) * noise ----------
__global__ __launch_bounds__(256) void vbuild_kernel(
    const float* __restrict__ outp, const float* __restrict__ noise,
    const float* __restrict__ reds, float* __restrict__ V)
{
    const int i = blockIdx.x * 256 + threadIdx.x;
    const int b = i >> 15;
    const float Mn = 1048576.f;
    const float S1 = reds[4 + b], S2 = reds[8 + b];
    const float var = (S2 - S1*S1/Mn) / (Mn - 1.f);
    const float vd = fmaxf(0.02f - var, 0.f);
    const float4 o = ((const float4*)outp)[i];
    const float4 n = ((const float4*)noise)[i];
    ((float4*)V)[i] = make_float4(o.x + vd*n.x, o.y + vd*n.y,
                                  o.z + vd*n.z, o.w + vd*n.w);
}

// ---------- K8a: split-K partials; grid 960 main + 512 pred ----------
__global__ __launch_bounds__(256) void av_part(
    const float* __restrict__ A, const float* __restrict__ V,
    float* __restrict__ P,
    const float* __restrict__ state, const float* __restrict__ w1,
    float* __restrict__ dout, int predBase)
{
    if (blockIdx.x >= 960) {
        pred_node(predBase + (int)blockIdx.x - 960, state, w1, dout);
        return;
    }
    const int bid = blockIdx.x;
    const int ks = bid & 3;
    const int rt = (bid >> 2) % 60;
    const int b  = bid / 240;
    const int r0 = NUM_IN + rt * 16;
    const int mc0 = ks << 8;
    const int t = threadIdx.x;
    const int d = t & 127, rg = t >> 7;
    const int rowb = r0 + rg*8;

    float acc[8] = {0.f,0.f,0.f,0.f,0.f,0.f,0.f,0.f};
    const float* Vb = V + ((size_t)b << 17) + ((size_t)mc0 << 7) + d;
    const float* Ab = A + (((size_t)(b*NN + rowb)) << 10) + mc0;

    #pragma unroll 4
    for (int mq = 0; mq < 64; ++mq) {
        const float v0 = Vb[(mq*4 + 0) << 7];
        const float v1 = Vb[(mq*4 + 1) << 7];
        const float v2 = Vb[(mq*4 + 2) << 7];
        const float v3 = Vb[(mq*4 + 3) << 7];
        #pragma unroll
        for (int k = 0; k < 8; ++k) {
            const float4 a = *(const float4*)(Ab + ((size_t)k << 10) + mq*4);
            acc[k] += a.x*v0 + a.y*v1 + a.z*v2 + a.w*v3;
        }
    }
    #pragma unroll
    for (int k = 0; k < 8; ++k) {
        const int ridx = rt*16 + rg*8 + k;
        P[(((size_t)(ks*NB + b)) * 960 + ridx) * 128 + d] = acc[k];
    }
}

// ---------- K8b: sum partials + softsign -> dout; env rows ----------
__global__ __launch_bounds__(256) void av_fin(
    const float* __restrict__ P, const float* __restrict__ env,
    float* __restrict__ dout)
{
    const int t = threadIdx.x;
    int bid = blockIdx.x;
    if (bid < 128) {
        const int idx = bid*256 + t;
        const int b = idx >> 13, off = idx & 8191;
        const int r = off >> 7, d = off & 127;
        dout[((size_t)(b*NN + r)) * OUT_STRIDE + d] = env[idx];
        return;
    }
    bid -= 128;
    const int idx = bid*256 + t;
    const int d = idx & 127;
    const int rd = idx >> 7;
    const int b = rd / 960;
    const int ridx = rd - b*960;
    const float s = P[idx] + P[idx + 491520] + P[idx + 2*491520] + P[idx + 3*491520];
    dout[((size_t)(b*NN + NUM_IN + ridx)) * OUT_STRIDE + d] = s / (1.f + fabsf(s));
}

extern "C" void kernel_launch(void* const* d_in, const int* in_sizes, int n_in,
                              void* d_out, int out_size, void* d_ws, size_t ws_size,
                              hipStream_t stream)
{
    (void)in_sizes; (void)n_in; (void)out_size; (void)ws_size;
    const float* state = (const float*)d_in[0];
    const float* outp  = (const float*)d_in[1];
    const float* w1    = (const float*)d_in[2];
    const float* w2    = (const float*)d_in[3];
    const float* w3    = (const float*)d_in[4];
    const float* A_ema = (const float*)d_in[5];
    const float* env   = (const float*)d_in[6];
    const float* noise = (const float*)d_in[7];
    float* dout = (float*)d_out;

    unsigned* M0  = (unsigned*)(dout + A_OFF);
    unsigned* M0T = M0 + 2097152;

    // ws layout (floats): Q | K | V | raw/A1 (2M u) | A1T (2M u) |
    //   SR1[4096] reds[16] cnt[32] | SC1[4096] SR2[4096] SC2[4096] RV1[4096] RV2[4096]
    float*    Qg   = (float*)d_ws;
    float*    Kg   = Qg + 524288;
    float*    Vg   = Kg + 524288;
    unsigned* raw  = (unsigned*)(Vg + 524288);   // reused as A1 after emaT
    unsigned* A1   = raw;
    unsigned* A1T  = raw + 2097152;
    float*    Pp   = (float*)A1T;                // av partials reuse A1T
    float*    SR1  = (float*)(A1T + 2097152);
    float*    reds = SR1 + 4096;
    unsigned* cnt  = (unsigned*)(reds + 16);     // cnt1 = cnt, cnt2 = cnt+16
    float*    SC1  = (float*)(cnt + 32);
    float*    SR2  = SC1 + 4096;
    float*    SC2  = SR2 + 4096;
    float*    RV1  = SC2 + 4096;
    float*    RV2  = RV1 + 4096;

    hipMemsetAsync(SR1, 0, (4096 + 16 + 32) * sizeof(float), stream);

    qk_kernel<<<dim3(NB*NN), dim3(256), 0, stream>>>(state, w2, w3, Qg, Kg);

    int pb = 0;
    qk2_kernel<<<dim3(4096 + 1536), dim3(256), 0, stream>>>(
        Qg, Kg, raw, reds, state, w1, dout, pb);
    pb += 1536;

    emaT_kernel<<<dim3(1024 + 768), dim3(256), 0, stream>>>(
        raw, A_ema, reds, M0, M0T, SR1, state, w1, dout, pb);
    pb += 768;

    // Sinkhorn call 1 (15 matvecs fused): in SR1 -> out RV1 (r8 inv), SC1 (c8 inv)
    {
        void* args[] = { (void*)&M0, (void*)&M0T, (void*)&SR1,
                         (void*)&SC1, (void*)&RV1, (void*)&cnt };
        hipLaunchCooperativeKernel((void*)sink_coop, dim3(256), dim3(1024),
                                   args, 0, stream);
    }

    thresh_kernel<<<dim3(256 + 768), dim3(256), 0, stream>>>(
        M0, M0T, RV1, SC1, A1, A1T, SR2, state, w1, dout, pb);
    pb += 768;

    // Sinkhorn call 2
    {
        unsigned* cnt2 = cnt + 16;
        void* args[] = { (void*)&A1, (void*)&A1T, (void*)&SR2,
                         (void*)&SC2, (void*)&RV2, (void*)&cnt2 };
        hipLaunchCooperativeKernel((void*)sink_coop, dim3(256), dim3(1024),
                                   args, 0, stream);
    }

    fin_kernel<<<dim3(256 + 512), dim3(256), 0, stream>>>(
        A1, RV2, SC2, reds, dout, state, w1, pb);
    pb += 512;

    vbuild_kernel<<<dim3(512), dim3(256), 0, stream>>>(outp, noise, reds, Vg);

    av_part<<<dim3(960 + 512), dim3(256), 0, stream>>>(
        dout + A_OFF, Vg, Pp, state, w1, dout, pb);
    pb += 512;   // == 4096

    av_fin<<<dim3(2048), dim3(256), 0, stream>>>(Pp, env, dout);
}

// Round 9
// 442.203 us; speedup vs baseline: 1.4116x; 1.4116x over previous
//
#include <hip/hip_runtime.h>
#include <math.h>

#define NB 4
#define NN 1024
#define ND 128
#define NUM_IN 64
#define F_EPS 1e-8f
#define BT_SCALE 1.8477590650225735f      // sqrt(2+sqrt(2))
#define INV_SQRT_D 0.08838834764831844f   // 1/sqrt(128)
#define BASELINE (1.0f/1025.0f)
#define OUT_STRIDE 256
#define A_OFF 1048576                     // floats: NB*NN*OUT_STRIDE

__device__ __forceinline__ float buntanh_f(float x) {
    return BT_SCALE * (0.5f * x + 0.5f * tanhf(x));
}
__device__ __forceinline__ float wave_sum(float v) {
    #pragma unroll
    for (int off = 32; off > 0; off >>= 1) v += __shfl_xor(v, off, 64);
    return v;
}
__device__ __forceinline__ float bflo(unsigned u) { return __uint_as_float(u << 16); }
__device__ __forceinline__ float bfhi(unsigned u) { return __uint_as_float(u & 0xffff0000u); }
__device__ __forceinline__ unsigned bf_rne(float f) {
    unsigned x = __float_as_uint(f);
    return (x + 0x7fffu + ((x >> 16) & 1u)) >> 16;
}
__device__ __forceinline__ unsigned bf_pack(float lo, float hi) {
    return bf_rne(lo) | (bf_rne(hi) << 16);
}

typedef float f32x4 __attribute__((ext_vector_type(4)));
__device__ __forceinline__ float4 ntload4(const float4* p) {
    f32x4 v = __builtin_nontemporal_load((const f32x4*)p);
    return make_float4(v.x, v.y, v.z, v.w);
}

// ---------- K1: per-node matvecs (w1,w2,w3 fused) -> prediction, K, Q ----------
__global__ __launch_bounds__(256, 8) void qkp_kernel(
    const float* __restrict__ state,
    const float* __restrict__ w1,
    const float* __restrict__ w2,
    const float* __restrict__ w3,
    float* __restrict__ dout,
    float* __restrict__ Qg,
    float* __restrict__ Kg)
{
    const int blk = blockIdx.x;
    const int node = ((blk & 7) << 9) | (blk >> 3);   // XCD-chunked

    __shared__ float s_state[ND];
    __shared__ float4 red[3][8][32];

    const int t = threadIdx.x;
    if (t < 32) ((float4*)s_state)[t] =
        ((const float4*)(state + ((size_t)node << 7)))[t];
    __syncthreads();

    const int g = t >> 5, m = t & 31;

    auto do_mat = [&](const float* wbase, int q) {
        const float4* w4 = (const float4*)(wbase + ((size_t)node << 14));
        float4 wv[8];
        float4 acc = make_float4(0.f, 0.f, 0.f, 0.f);
        #pragma unroll
        for (int i = 0; i < 8; ++i) wv[i] = ntload4(&w4[i*256 + t]);
        #pragma unroll
        for (int i = 0; i < 8; ++i) {
            const float s = s_state[i*8 + g];
            acc.x += s*wv[i].x; acc.y += s*wv[i].y;
            acc.z += s*wv[i].z; acc.w += s*wv[i].w;
        }
        #pragma unroll
        for (int i = 0; i < 8; ++i) wv[i] = ntload4(&w4[(8+i)*256 + t]);
        #pragma unroll
        for (int i = 0; i < 8; ++i) {
            const float s = s_state[(8+i)*8 + g];
            acc.x += s*wv[i].x; acc.y += s*wv[i].y;
            acc.z += s*wv[i].z; acc.w += s*wv[i].w;
        }
        red[q][g][m] = acc;
    };
    do_mat(w1, 0);
    do_mat(w2, 1);
    do_mat(w3, 2);
    __syncthreads();

    if (t < 96) {
        const int q = t >> 5, mm = t & 31;
        float4 o = red[q][0][mm];
        #pragma unroll
        for (int gg = 1; gg < 8; ++gg) {
            const float4 r = red[q][gg][mm];
            o.x += r.x; o.y += r.y; o.z += r.z; o.w += r.w;
        }
        o.x = buntanh_f(o.x); o.y = buntanh_f(o.y);
        o.z = buntanh_f(o.z); o.w = buntanh_f(o.w);
        if (q == 0) {
            *(float4*)(dout + (size_t)node * OUT_STRIDE + ND + 4*mm) = o;   // prediction
        } else {
            float* base = (q == 1) ? Kg : Qg;                               // w2->K, w3->Q
            *(float4*)(base + ((size_t)node << 7) + 4*mm) = o;
        }
    }
}

// ---------- K2: raw_A = Q K^T * inv_sqrt_d -> raw (bf16); ssq atomics ----------
__global__ __launch_bounds__(256) void qk2_kernel(
    const float* __restrict__ Qg, const float* __restrict__ Kg,
    unsigned* __restrict__ rawbf, float* __restrict__ reds)
{
    const int b = blockIdx.x >> 10;
    const int tile = blockIdx.x & 1023;
    const int tr = tile >> 5, tc = tile & 31;

    __shared__ float Qs[32][132];
    __shared__ float Ks[32][136];
    __shared__ float wr4[4];

    const int t = threadIdx.x;
    for (int i = t; i < 1024; i += 256) {
        const int r = i >> 5, q = i & 31;
        *(float4*)&Qs[r][q*4] = *(const float4*)(Qg + (((size_t)(b*NN + tr*32 + r)) << 7) + q*4);
        *(float4*)&Ks[r][q*4] = *(const float4*)(Kg + (((size_t)(b*NN + tc*32 + r)) << 7) + q*4);
    }
    __syncthreads();

    const int ty = t >> 4;        // rows ty, ty+16
    const int tx = t & 15;        // cols 2tx, 2tx+1
    float a00=0.f, a01=0.f, a10=0.f, a11=0.f;
    #pragma unroll
    for (int dq = 0; dq < 32; ++dq) {
        const float4 q0 = *(const float4*)&Qs[ty][dq*4];
        const float4 q1 = *(const float4*)&Qs[ty+16][dq*4];
        const float4 k0 = *(const float4*)&Ks[2*tx][dq*4];
        const float4 k1 = *(const float4*)&Ks[2*tx+1][dq*4];
        a00 += q0.x*k0.x + q0.y*k0.y + q0.z*k0.z + q0.w*k0.w;
        a01 += q0.x*k1.x + q0.y*k1.y + q0.z*k1.z + q0.w*k1.w;
        a10 += q1.x*k0.x + q1.y*k0.y + q1.z*k0.z + q1.w*k0.w;
        a11 += q1.x*k1.x + q1.y*k1.y + q1.z*k1.z + q1.w*k1.w;
    }
    a00 *= INV_SQRT_D; a01 *= INV_SQRT_D; a10 *= INV_SQRT_D; a11 *= INV_SQRT_D;

    unsigned* r0p = rawbf + (((size_t)(b*NN + tr*32 + ty)) << 9) + tc*16;
    unsigned* r1p = rawbf + (((size_t)(b*NN + tr*32 + ty + 16)) << 9) + tc*16;
    r0p[tx] = bf_pack(a00, a01);
    r1p[tx] = bf_pack(a10, a11);

    float ssq = a00*a00 + a01*a01 + a10*a10 + a11*a11;
    ssq = wave_sum(ssq);
    if ((t & 63) == 0) wr4[t >> 6] = ssq;
    __syncthreads();
    if (t == 0) atomicAdd(&reds[b], wr4[0]+wr4[1]+wr4[2]+wr4[3]);
}

// ---------- K3: EMA+mask+eps transform; write M0, M0^T (bf16); rowsum atomics ----------
__global__ __launch_bounds__(256) void emaT_kernel(
    const unsigned* __restrict__ rawbf, const float* __restrict__ A_ema,
    const float* __restrict__ reds,
    unsigned* __restrict__ M0, unsigned* __restrict__ M0T,
    float* __restrict__ SR)
{
    const int b = blockIdx.x >> 8;
    const int tile = blockIdx.x & 255;
    const int tr = tile >> 4, tc = tile & 15;
    const int R0 = tr << 6, C0 = tc << 6;

    __shared__ float st[64][65];
    __shared__ float s_part[64][5];

    const int t = threadIdx.x;
    const int r = t >> 2, q = t & 3;
    const int row = R0 + r;
    const float scale = rsqrtf(reds[b] * (1.0f/1048576.0f) + F_EPS);

    const unsigned* rawrow = rawbf + (((size_t)(b*NN + row)) << 9) + tc*8*4;
    const uint4 u0 = ((const uint4*)rawrow)[q*2];
    const uint4 u1 = ((const uint4*)rawrow)[q*2 + 1];
    float rv[16];
    rv[0]=bflo(u0.x); rv[1]=bfhi(u0.x); rv[2]=bflo(u0.y); rv[3]=bfhi(u0.y);
    rv[4]=bflo(u0.z); rv[5]=bfhi(u0.z); rv[6]=bflo(u0.w); rv[7]=bfhi(u0.w);
    rv[8]=bflo(u1.x); rv[9]=bfhi(u1.x); rv[10]=bflo(u1.y); rv[11]=bfhi(u1.y);
    rv[12]=bflo(u1.z); rv[13]=bfhi(u1.z); rv[14]=bflo(u1.w); rv[15]=bfhi(u1.w);

    const float* emarow = A_ema + (((size_t)(b*NN + row)) << 10) + C0 + q*16;
    float s = 0.f;
    #pragma unroll
    for (int j = 0; j < 4; ++j) {
        const float4 e = ((const float4*)emarow)[j];
        float ev[4] = {e.x, e.y, e.z, e.w};
        #pragma unroll
        for (int k = 0; k < 4; ++k) {
            const int e_idx = j*4 + k;
            const int c = C0 + q*16 + e_idx;
            float em = ev[k];
            if (row == NUM_IN && c < NUM_IN) em += 3.0f / NUM_IN;
            float v = em * 0.99f + rv[e_idx] * scale * 0.01f;
            if (row < NUM_IN) v = 0.f;
            v = fmaxf(v, 0.f) + F_EPS;
            rv[e_idx] = v;
            st[r][q*16 + e_idx] = v;
            s += v;
        }
    }
    s_part[r][q] = s;

    unsigned* m0row = M0 + (((size_t)(b*NN + row)) << 9) + tc*8*4;
    uint4 o0, o1;
    o0.x = bf_pack(rv[0],rv[1]);  o0.y = bf_pack(rv[2],rv[3]);
    o0.z = bf_pack(rv[4],rv[5]);  o0.w = bf_pack(rv[6],rv[7]);
    o1.x = bf_pack(rv[8],rv[9]);  o1.y = bf_pack(rv[10],rv[11]);
    o1.z = bf_pack(rv[12],rv[13]); o1.w = bf_pack(rv[14],rv[15]);
    ((uint4*)m0row)[q*2]     = o0;
    ((uint4*)m0row)[q*2 + 1] = o1;
    __syncthreads();

    if (t < 64) {
        const float rs = s_part[t][0] + s_part[t][1] + s_part[t][2] + s_part[t][3];
        atomicAdd(&SR[b*NN + R0 + t], rs);
    }

    const int cT = t >> 2;
    float tv[16];
    #pragma unroll
    for (int k = 0; k < 16; ++k) tv[k] = st[q*16 + k][cT];
    uint4 w0, w1;
    w0.x = bf_pack(tv[0],tv[1]);  w0.y = bf_pack(tv[2],tv[3]);
    w0.z = bf_pack(tv[4],tv[5]);  w0.w = bf_pack(tv[6],tv[7]);
    w1.x = bf_pack(tv[8],tv[9]);  w1.y = bf_pack(tv[10],tv[11]);
    w1.z = bf_pack(tv[12],tv[13]); w1.w = bf_pack(tv[14],tv[15]);
    unsigned* mtrow = M0T + (((size_t)(b*NN + C0 + cT)) << 9) + tr*8*4;
    ((uint4*)mtrow)[q*2]     = w0;
    ((uint4*)mtrow)[q*2 + 1] = w1;
}

// ---------- K4 x30: y = 1/(A . x)  (x already inverted unless INV_IN) ----------
// 512 blocks x 512 thr; ONE row per wave (no serial row chain)
template<bool INV_IN>
__global__ __launch_bounds__(512) void mv_kernel(
    const unsigned* __restrict__ Abf, const float* __restrict__ x,
    float* __restrict__ y)
{
    const int blk = blockIdx.x;
    const int lp  = ((blk & 7) << 6) | (blk >> 3);   // XCD-chunked, bijective on 512
    const int b   = lp >> 7;                         // 128 blocks/batch
    const int r0  = (lp & 127) << 3;                 // 8 rows/block
    const int t = threadIdx.x;
    const int w = t >> 6, l = t & 63;
    const int row = r0 + w;

    // lane l's vector slice: cols 8l..8l+7 and 512+8l..512+8l+7
    const float4* xb = (const float4*)(x + (b << 10));
    float4 x0 = xb[2*l], x1 = xb[2*l+1], x2 = xb[128+2*l], x3 = xb[129+2*l];
    if (INV_IN) {
        x0.x=1.f/x0.x; x0.y=1.f/x0.y; x0.z=1.f/x0.z; x0.w=1.f/x0.w;
        x1.x=1.f/x1.x; x1.y=1.f/x1.y; x1.z=1.f/x1.z; x1.w=1.f/x1.w;
        x2.x=1.f/x2.x; x2.y=1.f/x2.y; x2.z=1.f/x2.z; x2.w=1.f/x2.w;
        x3.x=1.f/x3.x; x3.y=1.f/x3.y; x3.z=1.f/x3.z; x3.w=1.f/x3.w;
    }

    const unsigned* rp = Abf + (((size_t)((b << 10) + row)) << 9);
    const uint4 v0 = ((const uint4*)rp)[l];
    const uint4 v1 = ((const uint4*)rp)[64 + l];
    float a = bflo(v0.x)*x0.x + bfhi(v0.x)*x0.y
            + bflo(v0.y)*x0.z + bfhi(v0.y)*x0.w
            + bflo(v0.z)*x1.x + bfhi(v0.z)*x1.y
            + bflo(v0.w)*x1.z + bfhi(v0.w)*x1.w
            + bflo(v1.x)*x2.x + bfhi(v1.x)*x2.y
            + bflo(v1.y)*x2.z + bfhi(v1.y)*x2.w
            + bflo(v1.z)*x3.x + bfhi(v1.z)*x3.y
            + bflo(v1.w)*x3.z + bfhi(v1.w)*x3.w;
    a = wave_sum(a);
    if (l == 0) y[(b << 10) + row] = 1.0f / a;
}

// ---------- K5: threshold+eps -> A1, A1^T (bf16); rowsums of A1 -> SR2 ----------
__global__ __launch_bounds__(256) void thresh_kernel(
    const unsigned* __restrict__ M0, const unsigned* __restrict__ M0T,
    const float* __restrict__ r8, const float* __restrict__ c8,
    unsigned* __restrict__ A1, unsigned* __restrict__ A1T,
    float* __restrict__ SR2)
{
    const int t = threadIdx.x;
    const int b = blockIdx.x >> 6;
    const int g0 = (blockIdx.x & 63) << 4;
    const int w = t >> 6, l = t & 63;
    const bool doA1 = (w < 2);
    const int wr = doA1 ? w : (w - 2);
    const unsigned* src = doA1 ? M0 : M0T;
    unsigned*       dst = doA1 ? A1 : A1T;
    const float* rowS = doA1 ? r8 : c8;
    const float* colS = doA1 ? c8 : r8;

    const float4* cb = (const float4*)(colS + (b << 10));
    const float4 c0 = cb[2*l], c1 = cb[2*l+1], c2 = cb[128+2*l], c3 = cb[129+2*l];
    const float cm[16] = {c0.x,c0.y,c0.z,c0.w, c1.x,c1.y,c1.z,c1.w,
                          c2.x,c2.y,c2.z,c2.w, c3.x,c3.y,c3.z,c3.w};

    for (int rr = 0; rr < 8; ++rr) {
        const int row = g0 + wr*8 + rr;
        const float ri = rowS[(b << 10) + row];
        const unsigned* rp = src + (((size_t)(b*NN + row)) << 9);
        const uint4 v0 = ((const uint4*)rp)[l];
        const uint4 v1 = ((const uint4*)rp)[64 + l];
        float e[16];
        e[0]=bflo(v0.x); e[1]=bfhi(v0.x); e[2]=bflo(v0.y); e[3]=bfhi(v0.y);
        e[4]=bflo(v0.z); e[5]=bfhi(v0.z); e[6]=bflo(v0.w); e[7]=bfhi(v0.w);
        e[8]=bflo(v1.x); e[9]=bfhi(v1.x); e[10]=bflo(v1.y); e[11]=bfhi(v1.y);
        e[12]=bflo(v1.z); e[13]=bfhi(v1.z); e[14]=bflo(v1.w); e[15]=bfhi(v1.w);
        float s = 0.f;
        #pragma unroll
        for (int j = 0; j < 16; ++j) {
            const float d = e[j] * ri * cm[j];
            e[j] = (d > BASELINE ? d : 0.f) + F_EPS;
            s += e[j];
        }
        uint4 o0, o1;
        o0.x = bf_pack(e[0],e[1]);  o0.y = bf_pack(e[2],e[3]);
        o0.z = bf_pack(e[4],e[5]);  o0.w = bf_pack(e[6],e[7]);
        o1.x = bf_pack(e[8],e[9]);  o1.y = bf_pack(e[10],e[11]);
        o1.z = bf_pack(e[12],e[13]); o1.w = bf_pack(e[14],e[15]);
        unsigned* op = dst + (((size_t)(b*NN + row)) << 9);
        ((uint4*)op)[l] = o0;
        ((uint4*)op)[64 + l] = o1;
        if (doA1) {
            s = wave_sum(s);
            if (l == 0) SR2[b*NN + row] = s;
        }
    }
}

// ---------- K6: final scale + mask -> A (fp32, dout); variance partials ----------
__global__ __launch_bounds__(256) void fin_kernel(
    const unsigned* __restrict__ A1, const float* __restrict__ r8,
    const float* __restrict__ c8, float* __restrict__ reds,
    float* __restrict__ dout)
{
    __shared__ float wred[8];
    const int t = threadIdx.x;
    const int b = blockIdx.x >> 6;
    const int g0 = (blockIdx.x & 63) << 4;
    const int w = t >> 6, l = t & 63;

    const float4* cb = (const float4*)(c8 + (b << 10));
    const float4 c0 = cb[2*l], c1 = cb[2*l+1], c2 = cb[128+2*l], c3 = cb[129+2*l];
    const float cm[16] = {c0.x,c0.y,c0.z,c0.w, c1.x,c1.y,c1.z,c1.w,
                          c2.x,c2.y,c2.z,c2.w, c3.x,c3.y,c3.z,c3.w};

    float s1 = 0.f, s2 = 0.f;
    for (int rr = 0; rr < 4; ++rr) {
        const int row = g0 + w*4 + rr;
        float* Arow = dout + A_OFF + (((size_t)(b*NN + row)) << 10);
        if (row < NUM_IN) {
            const float4 z = make_float4(0.f,0.f,0.f,0.f);
            ((float4*)Arow)[2*l] = z;       ((float4*)Arow)[2*l+1] = z;
            ((float4*)Arow)[128+2*l] = z;   ((float4*)Arow)[129+2*l] = z;
        } else {
            const float ri = r8[(b << 10) + row];
            const unsigned* rp = A1 + (((size_t)(b*NN + row)) << 9);
            const uint4 v0 = ((const uint4*)rp)[l];
            const uint4 v1 = ((const uint4*)rp)[64 + l];
            float e[16];
            e[0]=bflo(v0.x); e[1]=bfhi(v0.x); e[2]=bflo(v0.y); e[3]=bfhi(v0.y);
            e[4]=bflo(v0.z); e[5]=bfhi(v0.z); e[6]=bflo(v0.w); e[7]=bfhi(v0.w);
            e[8]=bflo(v1.x); e[9]=bfhi(v1.x); e[10]=bflo(v1.y); e[11]=bfhi(v1.y);
            e[12]=bflo(v1.z); e[13]=bfhi(v1.z); e[14]=bflo(v1.w); e[15]=bfhi(v1.w);
            #pragma unroll
            for (int j = 0; j < 16; ++j) {
                e[j] = e[j] * ri * cm[j];
                s1 += e[j]; s2 += e[j]*e[j];
            }
            ((float4*)Arow)[2*l]     = make_float4(e[0],e[1],e[2],e[3]);
            ((float4*)Arow)[2*l+1]   = make_float4(e[4],e[5],e[6],e[7]);
            ((float4*)Arow)[128+2*l] = make_float4(e[8],e[9],e[10],e[11]);
            ((float4*)Arow)[129+2*l] = make_float4(e[12],e[13],e[14],e[15]);
        }
    }
    s1 = wave_sum(s1); s2 = wave_sum(s2);
    if (l == 0) { wred[w] = s1; wred[4 + w] = s2; }
    __syncthreads();
    if (t == 0) {
        atomicAdd(&reds[4 + b], wred[0]+wred[1]+wred[2]+wred[3]);
        atomicAdd(&reds[8 + b], wred[4]+wred[5]+wred[6]+wred[7]);
    }
}

// ---------- K7: V = output + relu(0.02 - var) * noise ----------
__global__ __launch_bounds__(256) void vbuild_kernel(
    const float* __restrict__ outp, const float* __restrict__ noise,
    const float* __restrict__ reds, float* __restrict__ V)
{
    const int i = blockIdx.x * 256 + threadIdx.x;   // float4 idx, 131072 total
    const int b = i >> 15;
    const float Mn = 1048576.f;
    const float S1 = reds[4 + b], S2 = reds[8 + b];
    const float var = (S2 - S1*S1/Mn) / (Mn - 1.f);
    const float vd = fmaxf(0.02f - var, 0.f);
    const float4 o = ((const float4*)outp)[i];
    const float4 n = ((const float4*)noise)[i];
    ((float4*)V)[i] = make_float4(o.x + vd*n.x, o.y + vd*n.y,
                                  o.z + vd*n.z, o.w + vd*n.w);
}

// ---------- K8a: split-K partials; 480 blocks x 512 thr, 32 rows/block ----------
__global__ __launch_bounds__(512) void av_part(
    const float* __restrict__ A,       // dout + A_OFF (fp32)
    const float* __restrict__ V,
    float* __restrict__ P)
{
    const int bid = blockIdx.x;
    const int ks = bid & 3;
    const int rt = (bid >> 2) % 30;
    const int b  = bid / 120;
    const int r0 = NUM_IN + rt * 32;
    const int mc0 = ks << 8;
    const int t = threadIdx.x;
    const int d = t & 127, rg = t >> 7;    // rg 0..3
    const int rowb = r0 + rg*8;

    float acc[8] = {0.f,0.f,0.f,0.f,0.f,0.f,0.f,0.f};
    const float* Vb = V + ((size_t)b << 17) + ((size_t)mc0 << 7) + d;
    const float* Ab = A + (((size_t)(b*NN + rowb)) << 10) + mc0;

    #pragma unroll 4
    for (int mq = 0; mq < 64; ++mq) {
        const float v0 = Vb[(mq*4 + 0) << 7];
        const float v1 = Vb[(mq*4 + 1) << 7];
        const float v2 = Vb[(mq*4 + 2) << 7];
        const float v3 = Vb[(mq*4 + 3) << 7];
        #pragma unroll
        for (int k = 0; k < 8; ++k) {
            const float4 a = *(const float4*)(Ab + ((size_t)k << 10) + mq*4);
            acc[k] += a.x*v0 + a.y*v1 + a.z*v2 + a.w*v3;
        }
    }
    #pragma unroll
    for (int k = 0; k < 8; ++k) {
        const int ridx = rt*32 + rg*8 + k;
        P[(((size_t)(ks*NB + b)) * 960 + ridx) * 128 + d] = acc[k];
    }
}

// ---------- K8b: sum partials + softsign -> dout; env rows overwrite ----------
__global__ __launch_bounds__(256) void av_fin(
    const float* __restrict__ P, const float* __restrict__ env,
    float* __restrict__ dout)
{
    const int t = threadIdx.x;
    int bid = blockIdx.x;
    if (bid < 128) {
        const int idx = bid*256 + t;         // 0..32767 over [4][8192]
        const int b = idx >> 13, off = idx & 8191;
        const int r = off >> 7, d = off & 127;
        dout[((size_t)(b*NN + r)) * OUT_STRIDE + d] = env[idx];
        return;
    }
    bid -= 128;
    const int idx = bid*256 + t;             // 0..491519 over [4][960][128]
    const int d = idx & 127;
    const int rd = idx >> 7;                 // b*960 + ridx
    const int b = rd / 960;
    const int ridx = rd - b*960;
    const float s = P[idx] + P[idx + 491520] + P[idx + 2*491520] + P[idx + 3*491520];
    dout[((size_t)(b*NN + NUM_IN + ridx)) * OUT_STRIDE + d] = s / (1.f + fabsf(s));
}

extern "C" void kernel_launch(void* const* d_in, const int* in_sizes, int n_in,
                              void* d_out, int out_size, void* d_ws, size_t ws_size,
                              hipStream_t stream)
{
    (void)in_sizes; (void)n_in; (void)out_size; (void)ws_size;
    const float* state = (const float*)d_in[0];
    const float* outp  = (const float*)d_in[1];
    const float* w1    = (const float*)d_in[2];
    const float* w2    = (const float*)d_in[3];
    const float* w3    = (const float*)d_in[4];
    const float* A_ema = (const float*)d_in[5];
    const float* env   = (const float*)d_in[6];
    const float* noise = (const float*)d_in[7];
    float* dout = (float*)d_out;

    // M0 / M0^T live in dout's A-region (dead until fin overwrites it with A)
    unsigned* M0  = (unsigned*)(dout + A_OFF);
    unsigned* M0T = M0 + 2097152;

    // ws layout (floats): Q(512K) K(512K) V(512K) | raw/A1 (2M u) | A1T (2M u) | vecs
    float*    Qg   = (float*)d_ws;
    float*    Kg   = Qg + 524288;
    float*    Vg   = Kg + 524288;
    unsigned* raw  = (unsigned*)(Vg + 524288);   // reused as A1 after emaT
    unsigned* A1   = raw;
    unsigned* A1T  = raw + 2097152;
    float*    Pp   = (float*)A1T;                // av partials reuse A1T (dead by then)
    float*    SR1  = (float*)(A1T + 2097152);    // [4][1024] sums (atomics)
    float*    reds = SR1 + 4096;                 // [16]
    float*    SC1  = reds + 16;                  // inverted c-vector
    float*    SR2  = SC1 + 4096;                 // sums after thresh
    float*    SC2  = SR2 + 4096;
    float*    RV1  = SC2 + 4096;                 // inverted r-vector (call 1)
    float*    RV2  = RV1 + 4096;                 // inverted r-vector (call 2)

    hipMemsetAsync(SR1, 0, (4096 + 16) * sizeof(float), stream);  // SR1 + reds

    qkp_kernel<<<dim3(NB*NN), dim3(256), 0, stream>>>(
        state, w1, w2, w3, dout, Qg, Kg);

    qk2_kernel<<<dim3(NB*1024), dim3(256), 0, stream>>>(Qg, Kg, raw, reds);

    emaT_kernel<<<dim3(NB*256), dim3(256), 0, stream>>>(
        raw, A_ema, reds, M0, M0T, SR1);

    // Sinkhorn call 1: c1 = 1/(M0T . (1/SR1)); then alternate. 15 matvecs.
    mv_kernel<true ><<<dim3(512), dim3(512), 0, stream>>>(M0T, SR1, SC1);
    for (int k = 1; k < 15; ++k) {
        if (k & 1)
            mv_kernel<false><<<dim3(512), dim3(512), 0, stream>>>(M0, SC1, RV1);
        else
            mv_kernel<false><<<dim3(512), dim3(512), 0, stream>>>(M0T, RV1, SC1);
    }
    // after loop: RV1 = r8 (inv), SC1 = c8 (inv)

    thresh_kernel<<<dim3(NB*64), dim3(256), 0, stream>>>(
        M0, M0T, RV1, SC1, A1, A1T, SR2);

    // Sinkhorn call 2
    mv_kernel<true ><<<dim3(512), dim3(512), 0, stream>>>(A1T, SR2, SC2);
    for (int k = 1; k < 15; ++k) {
        if (k & 1)
            mv_kernel<false><<<dim3(512), dim3(512), 0, stream>>>(A1, SC2, RV2);
        else
            mv_kernel<false><<<dim3(512), dim3(512), 0, stream>>>(A1T, RV2, SC2);
    }

    fin_kernel<<<dim3(NB*64), dim3(256), 0, stream>>>(A1, RV2, SC2, reds, dout);

    vbuild_kernel<<<dim3(512), dim3(256), 0, stream>>>(outp, noise, reds, Vg);

    av_part<<<dim3(480), dim3(512), 0, stream>>>(dout + A_OFF, Vg, Pp);

    av_fin<<<dim3(2048), dim3(256), 0, stream>>>(Pp, env, dout);
}

// Round 10
// 441.790 us; speedup vs baseline: 1.4130x; 1.0009x over previous
//
#include <hip/hip_runtime.h>
#include <math.h>

#define NB 4
#define NN 1024
#define ND 128
#define NUM_IN 64
#define F_EPS 1e-8f
#define BT_SCALE 1.8477590650225735f      // sqrt(2+sqrt(2))
#define INV_SQRT_D 0.08838834764831844f   // 1/sqrt(128)
#define BASELINE (1.0f/1025.0f)
#define OUT_STRIDE 256
#define A_OFF 1048576                     // floats: NB*NN*OUT_STRIDE

__device__ __forceinline__ float buntanh_f(float x) {
    return BT_SCALE * (0.5f * x + 0.5f * tanhf(x));
}
__device__ __forceinline__ float wave_sum(float v) {
    #pragma unroll
    for (int off = 32; off > 0; off >>= 1) v += __shfl_xor(v, off, 64);
    return v;
}
__device__ __forceinline__ float bflo(unsigned u) { return __uint_as_float(u << 16); }
__device__ __forceinline__ float bfhi(unsigned u) { return __uint_as_float(u & 0xffff0000u); }
__device__ __forceinline__ unsigned bf_rne(float f) {
    unsigned x = __float_as_uint(f);
    return (x + 0x7fffu + ((x >> 16) & 1u)) >> 16;
}
__device__ __forceinline__ unsigned bf_pack(float lo, float hi) {
    return bf_rne(lo) | (bf_rne(hi) << 16);
}

typedef float f32x4 __attribute__((ext_vector_type(4)));
__device__ __forceinline__ float4 ntload4(const float4* p) {
    f32x4 v = __builtin_nontemporal_load((const f32x4*)p);
    return make_float4(v.x, v.y, v.z, v.w);
}

// ---------- piggyback: one node's prediction = buntanh(state . w1) ----------
// run by one 256-thread block; self-contained (4KB LDS for reduction)
__device__ __forceinline__ void pred_node(
    const int node, const float* __restrict__ state,
    const float* __restrict__ w1, float* __restrict__ dout)
{
    __shared__ float4 pred_red[8][32];
    const int t = threadIdx.x;
    const int g = t >> 5, m = t & 31;
    const float4* w4 = (const float4*)(w1 + ((size_t)node << 14));
    const float* srow = state + ((size_t)node << 7);
    float4 acc = make_float4(0.f, 0.f, 0.f, 0.f);
    #pragma unroll
    for (int h = 0; h < 2; ++h) {
        float4 wv[8];
        #pragma unroll
        for (int i = 0; i < 8; ++i) wv[i] = ntload4(&w4[(h*8 + i)*256 + t]);
        #pragma unroll
        for (int i = 0; i < 8; ++i) {
            const float s = srow[(h*8 + i)*8 + g];
            acc.x += s*wv[i].x; acc.y += s*wv[i].y;
            acc.z += s*wv[i].z; acc.w += s*wv[i].w;
        }
    }
    pred_red[g][m] = acc;
    __syncthreads();
    if (t < 32) {
        float4 o = pred_red[0][t];
        #pragma unroll
        for (int gg = 1; gg < 8; ++gg) {
            const float4 r = pred_red[gg][t];
            o.x += r.x; o.y += r.y; o.z += r.z; o.w += r.w;
        }
        o.x = buntanh_f(o.x); o.y = buntanh_f(o.y);
        o.z = buntanh_f(o.z); o.w = buntanh_f(o.w);
        *(float4*)(dout + (size_t)node * OUT_STRIDE + ND + 4*t) = o;
    }
}

// ---------- K1: per-node matvecs (w2,w3) -> K, Q ----------
__global__ __launch_bounds__(256, 8) void qk_kernel(
    const float* __restrict__ state,
    const float* __restrict__ w2,
    const float* __restrict__ w3,
    float* __restrict__ Qg,
    float* __restrict__ Kg)
{
    const int blk = blockIdx.x;
    const int node = ((blk & 7) << 9) | (blk >> 3);   // XCD-chunked

    __shared__ float s_state[ND];
    __shared__ float4 red[2][8][32];

    const int t = threadIdx.x;
    if (t < 32) ((float4*)s_state)[t] =
        ((const float4*)(state + ((size_t)node << 7)))[t];
    __syncthreads();

    const int g = t >> 5, m = t & 31;

    auto do_mat = [&](const float* wbase, int q) {
        const float4* w4 = (const float4*)(wbase + ((size_t)node << 14));
        float4 wv[8];
        float4 acc = make_float4(0.f, 0.f, 0.f, 0.f);
        #pragma unroll
        for (int i = 0; i < 8; ++i) wv[i] = ntload4(&w4[i*256 + t]);
        #pragma unroll
        for (int i = 0; i < 8; ++i) {
            const float s = s_state[i*8 + g];
            acc.x += s*wv[i].x; acc.y += s*wv[i].y;
            acc.z += s*wv[i].z; acc.w += s*wv[i].w;
        }
        #pragma unroll
        for (int i = 0; i < 8; ++i) wv[i] = ntload4(&w4[(8+i)*256 + t]);
        #pragma unroll
        for (int i = 0; i < 8; ++i) {
            const float s = s_state[(8+i)*8 + g];
            acc.x += s*wv[i].x; acc.y += s*wv[i].y;
            acc.z += s*wv[i].z; acc.w += s*wv[i].w;
        }
        red[q][g][m] = acc;
    };
    do_mat(w2, 0);      // -> K
    do_mat(w3, 1);      // -> Q
    __syncthreads();

    if (t < 64) {
        const int q = t >> 5, mm = t & 31;
        float4 o = red[q][0][mm];
        #pragma unroll
        for (int gg = 1; gg < 8; ++gg) {
            const float4 r = red[q][gg][mm];
            o.x += r.x; o.y += r.y; o.z += r.z; o.w += r.w;
        }
        o.x = buntanh_f(o.x); o.y = buntanh_f(o.y);
        o.z = buntanh_f(o.z); o.w = buntanh_f(o.w);
        float* base = (q == 0) ? Kg : Qg;
        *(float4*)(base + ((size_t)node << 7) + 4*mm) = o;
    }
}

// ---------- K2: raw_A = Q K^T * inv_sqrt_d -> raw (bf16); ssq atomics ----------
// grid: 4096 main + 512 pred
__global__ __launch_bounds__(256) void qk2_kernel(
    const float* __restrict__ Qg, const float* __restrict__ Kg,
    unsigned* __restrict__ rawbf, float* __restrict__ reds,
    const float* __restrict__ state, const float* __restrict__ w1,
    float* __restrict__ dout, int predBase)
{
    if (blockIdx.x >= 4096) {
        pred_node(predBase + (int)blockIdx.x - 4096, state, w1, dout);
        return;
    }
    const int b = blockIdx.x >> 10;
    const int tile = blockIdx.x & 1023;
    const int tr = tile >> 5, tc = tile & 31;

    __shared__ float Qs[32][132];
    __shared__ float Ks[32][136];
    __shared__ float wr4[4];

    const int t = threadIdx.x;
    for (int i = t; i < 1024; i += 256) {
        const int r = i >> 5, q = i & 31;
        *(float4*)&Qs[r][q*4] = *(const float4*)(Qg + (((size_t)(b*NN + tr*32 + r)) << 7) + q*4);
        *(float4*)&Ks[r][q*4] = *(const float4*)(Kg + (((size_t)(b*NN + tc*32 + r)) << 7) + q*4);
    }
    __syncthreads();

    const int ty = t >> 4;
    const int tx = t & 15;
    float a00=0.f, a01=0.f, a10=0.f, a11=0.f;
    #pragma unroll
    for (int dq = 0; dq < 32; ++dq) {
        const float4 q0 = *(const float4*)&Qs[ty][dq*4];
        const float4 q1 = *(const float4*)&Qs[ty+16][dq*4];
        const float4 k0 = *(const float4*)&Ks[2*tx][dq*4];
        const float4 k1 = *(const float4*)&Ks[2*tx+1][dq*4];
        a00 += q0.x*k0.x + q0.y*k0.y + q0.z*k0.z + q0.w*k0.w;
        a01 += q0.x*k1.x + q0.y*k1.y + q0.z*k1.z + q0.w*k1.w;
        a10 += q1.x*k0.x + q1.y*k0.y + q1.z*k0.z + q1.w*k0.w;
        a11 += q1.x*k1.x + q1.y*k1.y + q1.z*k1.z + q1.w*k1.w;
    }
    a00 *= INV_SQRT_D; a01 *= INV_SQRT_D; a10 *= INV_SQRT_D; a11 *= INV_SQRT_D;

    unsigned* r0p = rawbf + (((size_t)(b*NN + tr*32 + ty)) << 9) + tc*16;
    unsigned* r1p = rawbf + (((size_t)(b*NN + tr*32 + ty + 16)) << 9) + tc*16;
    r0p[tx] = bf_pack(a00, a01);
    r1p[tx] = bf_pack(a10, a11);

    float ssq = a00*a00 + a01*a01 + a10*a10 + a11*a11;
    ssq = wave_sum(ssq);
    if ((t & 63) == 0) wr4[t >> 6] = ssq;
    __syncthreads();
    if (t == 0) atomicAdd(&reds[b], wr4[0]+wr4[1]+wr4[2]+wr4[3]);
}

// ---------- K3: EMA+mask+eps; write M0, M0^T (bf16); rowsum atomics ----------
// grid: 1024 main + 512 pred
__global__ __launch_bounds__(256) void emaT_kernel(
    const unsigned* __restrict__ rawbf, const float* __restrict__ A_ema,
    const float* __restrict__ reds,
    unsigned* __restrict__ M0, unsigned* __restrict__ M0T,
    float* __restrict__ SR,
    const float* __restrict__ state, const float* __restrict__ w1,
    float* __restrict__ dout, int predBase)
{
    if (blockIdx.x >= 1024) {
        pred_node(predBase + (int)blockIdx.x - 1024, state, w1, dout);
        return;
    }
    const int b = blockIdx.x >> 8;
    const int tile = blockIdx.x & 255;
    const int tr = tile >> 4, tc = tile & 15;
    const int R0 = tr << 6, C0 = tc << 6;

    __shared__ float st[64][65];
    __shared__ float s_part[64][5];

    const int t = threadIdx.x;
    const int r = t >> 2, q = t & 3;
    const int row = R0 + r;
    const float scale = rsqrtf(reds[b] * (1.0f/1048576.0f) + F_EPS);

    const unsigned* rawrow = rawbf + (((size_t)(b*NN + row)) << 9) + tc*8*4;
    const uint4 u0 = ((const uint4*)rawrow)[q*2];
    const uint4 u1 = ((const uint4*)rawrow)[q*2 + 1];
    float rv[16];
    rv[0]=bflo(u0.x); rv[1]=bfhi(u0.x); rv[2]=bflo(u0.y); rv[3]=bfhi(u0.y);
    rv[4]=bflo(u0.z); rv[5]=bfhi(u0.z); rv[6]=bflo(u0.w); rv[7]=bfhi(u0.w);
    rv[8]=bflo(u1.x); rv[9]=bfhi(u1.x); rv[10]=bflo(u1.y); rv[11]=bfhi(u1.y);
    rv[12]=bflo(u1.z); rv[13]=bfhi(u1.z); rv[14]=bflo(u1.w); rv[15]=bfhi(u1.w);

    const float* emarow = A_ema + (((size_t)(b*NN + row)) << 10) + C0 + q*16;
    float s = 0.f;
    #pragma unroll
    for (int j = 0; j < 4; ++j) {
        const float4 e = ((const float4*)emarow)[j];
        float ev[4] = {e.x, e.y, e.z, e.w};
        #pragma unroll
        for (int k = 0; k < 4; ++k) {
            const int e_idx = j*4 + k;
            const int c = C0 + q*16 + e_idx;
            float em = ev[k];
            if (row == NUM_IN && c < NUM_IN) em += 3.0f / NUM_IN;
            float v = em * 0.99f + rv[e_idx] * scale * 0.01f;
            if (row < NUM_IN) v = 0.f;
            v = fmaxf(v, 0.f) + F_EPS;
            rv[e_idx] = v;
            st[r][q*16 + e_idx] = v;
            s += v;
        }
    }
    s_part[r][q] = s;

    unsigned* m0row = M0 + (((size_t)(b*NN + row)) << 9) + tc*8*4;
    uint4 o0, o1;
    o0.x = bf_pack(rv[0],rv[1]);  o0.y = bf_pack(rv[2],rv[3]);
    o0.z = bf_pack(rv[4],rv[5]);  o0.w = bf_pack(rv[6],rv[7]);
    o1.x = bf_pack(rv[8],rv[9]);  o1.y = bf_pack(rv[10],rv[11]);
    o1.z = bf_pack(rv[12],rv[13]); o1.w = bf_pack(rv[14],rv[15]);
    ((uint4*)m0row)[q*2]     = o0;
    ((uint4*)m0row)[q*2 + 1] = o1;
    __syncthreads();

    if (t < 64) {
        const float rs = s_part[t][0] + s_part[t][1] + s_part[t][2] + s_part[t][3];
        atomicAdd(&SR[b*NN + R0 + t], rs);
    }

    const int cT = t >> 2;
    float tv[16];
    #pragma unroll
    for (int k = 0; k < 16; ++k) tv[k] = st[q*16 + k][cT];
    uint4 w0, w1v;
    w0.x = bf_pack(tv[0],tv[1]);  w0.y = bf_pack(tv[2],tv[3]);
    w0.z = bf_pack(tv[4],tv[5]);  w0.w = bf_pack(tv[6],tv[7]);
    w1v.x = bf_pack(tv[8],tv[9]);  w1v.y = bf_pack(tv[10],tv[11]);
    w1v.z = bf_pack(tv[12],tv[13]); w1v.w = bf_pack(tv[14],tv[15]);
    unsigned* mtrow = M0T + (((size_t)(b*NN + C0 + cT)) << 9) + tr*8*4;
    ((uint4*)mtrow)[q*2]     = w0;
    ((uint4*)mtrow)[q*2 + 1] = w1v;
}

// ---------- K4 x30: y = 1/(A . x); one row per wave; grid 1024 main + 64 pred ----------
template<bool INV_IN>
__global__ __launch_bounds__(256) void mv_kernel(
    const unsigned* __restrict__ Abf, const float* __restrict__ x,
    float* __restrict__ y,
    const float* __restrict__ state, const float* __restrict__ w1,
    float* __restrict__ dout, int predBase)
{
    const int blk = blockIdx.x;
    if (blk >= 1024) {
        pred_node(predBase + blk - 1024, state, w1, dout);
        return;
    }
    const int lp  = ((blk & 7) << 7) | (blk >> 3);   // XCD-chunked, bijective on 1024
    const int b   = lp >> 8;                         // 256 blocks/batch
    const int r0  = (lp & 255) << 2;                 // 4 rows/block (1 per wave)
    const int t = threadIdx.x;
    const int w = t >> 6, l = t & 63;
    const int row = r0 + w;

    // lane l's vector slice: cols 8l..8l+7 and 512+8l..512+8l+7
    const float4* xb = (const float4*)(x + (b << 10));
    float4 x0 = xb[2*l], x1 = xb[2*l+1], x2 = xb[128+2*l], x3 = xb[129+2*l];
    if (INV_IN) {
        x0.x=1.f/x0.x; x0.y=1.f/x0.y; x0.z=1.f/x0.z; x0.w=1.f/x0.w;
        x1.x=1.f/x1.x; x1.y=1.f/x1.y; x1.z=1.f/x1.z; x1.w=1.f/x1.w;
        x2.x=1.f/x2.x; x2.y=1.f/x2.y; x2.z=1.f/x2.z; x2.w=1.f/x2.w;
        x3.x=1.f/x3.x; x3.y=1.f/x3.y; x3.z=1.f/x3.z; x3.w=1.f/x3.w;
    }

    const unsigned* rp = Abf + (((size_t)((b << 10) + row)) << 9);
    const uint4 v0 = ((const uint4*)rp)[l];
    const uint4 v1 = ((const uint4*)rp)[64 + l];
    float a = bflo(v0.x)*x0.x + bfhi(v0.x)*x0.y
            + bflo(v0.y)*x0.z + bfhi(v0.y)*x0.w
            + bflo(v0.z)*x1.x + bfhi(v0.z)*x1.y
            + bflo(v0.w)*x1.z + bfhi(v0.w)*x1.w
            + bflo(v1.x)*x2.x + bfhi(v1.x)*x2.y
            + bflo(v1.y)*x2.z + bfhi(v1.y)*x2.w
            + bflo(v1.z)*x3.x + bfhi(v1.z)*x3.y
            + bflo(v1.w)*x3.z + bfhi(v1.w)*x3.w;
    a = wave_sum(a);
    if (l == 0) y[(b << 10) + row] = 1.0f / a;
}

// ---------- K5: threshold+eps -> A1, A1^T (bf16); rowsums -> SR2 ----------
// grid 256 main + 384 pred
__global__ __launch_bounds__(256) void thresh_kernel(
    const unsigned* __restrict__ M0, const unsigned* __restrict__ M0T,
    const float* __restrict__ r8, const float* __restrict__ c8,
    unsigned* __restrict__ A1, unsigned* __restrict__ A1T,
    float* __restrict__ SR2,
    const float* __restrict__ state, const float* __restrict__ w1,
    float* __restrict__ dout, int predBase)
{
    if (blockIdx.x >= 256) {
        pred_node(predBase + (int)blockIdx.x - 256, state, w1, dout);
        return;
    }
    const int t = threadIdx.x;
    const int b = blockIdx.x >> 6;
    const int g0 = (blockIdx.x & 63) << 4;
    const int w = t >> 6, l = t & 63;
    const bool doA1 = (w < 2);
    const int wr = doA1 ? w : (w - 2);
    const unsigned* src = doA1 ? M0 : M0T;
    unsigned*       dst = doA1 ? A1 : A1T;
    const float* rowS = doA1 ? r8 : c8;
    const float* colS = doA1 ? c8 : r8;

    const float4* cb = (const float4*)(colS + (b << 10));
    const float4 c0 = cb[2*l], c1 = cb[2*l+1], c2 = cb[128+2*l], c3 = cb[129+2*l];
    const float cm[16] = {c0.x,c0.y,c0.z,c0.w, c1.x,c1.y,c1.z,c1.w,
                          c2.x,c2.y,c2.z,c2.w, c3.x,c3.y,c3.z,c3.w};

    for (int rr = 0; rr < 8; ++rr) {
        const int row = g0 + wr*8 + rr;
        const float ri = rowS[(b << 10) + row];
        const unsigned* rp = src + (((size_t)(b*NN + row)) << 9);
        const uint4 v0 = ((const uint4*)rp)[l];
        const uint4 v1 = ((const uint4*)rp)[64 + l];
        float e[16];
        e[0]=bflo(v0.x); e[1]=bfhi(v0.x); e[2]=bflo(v0.y); e[3]=bfhi(v0.y);
        e[4]=bflo(v0.z); e[5]=bfhi(v0.z); e[6]=bflo(v0.w); e[7]=bfhi(v0.w);
        e[8]=bflo(v1.x); e[9]=bfhi(v1.x); e[10]=bflo(v1.y); e[11]=bfhi(v1.y);
        e[12]=bflo(v1.z); e[13]=bfhi(v1.z); e[14]=bflo(v1.w); e[15]=bfhi(v1.w);
        float s = 0.f;
        #pragma unroll
        for (int j = 0; j < 16; ++j) {
            const float d = e[j] * ri * cm[j];
            e[j] = (d > BASELINE ? d : 0.f) + F_EPS;
            s += e[j];
        }
        uint4 o0, o1;
        o0.x = bf_pack(e[0],e[1]);  o0.y = bf_pack(e[2],e[3]);
        o0.z = bf_pack(e[4],e[5]);  o0.w = bf_pack(e[6],e[7]);
        o1.x = bf_pack(e[8],e[9]);  o1.y = bf_pack(e[10],e[11]);
        o1.z = bf_pack(e[12],e[13]); o1.w = bf_pack(e[14],e[15]);
        unsigned* op = dst + (((size_t)(b*NN + row)) << 9);
        ((uint4*)op)[l] = o0;
        ((uint4*)op)[64 + l] = o1;
        if (doA1) {
            s = wave_sum(s);
            if (l == 0) SR2[b*NN + row] = s;
        }
    }
}

// ---------- K6: final scale + mask -> A (fp32); variance partials ----------
// grid 256 main + 384 pred
__global__ __launch_bounds__(256) void fin_kernel(
    const unsigned* __restrict__ A1, const float* __restrict__ r8,
    const float* __restrict__ c8, float* __restrict__ reds,
    float* __restrict__ dout,
    const float* __restrict__ state, const float* __restrict__ w1,
    int predBase)
{
    if (blockIdx.x >= 256) {
        pred_node(predBase + (int)blockIdx.x - 256, state, w1, dout);
        return;
    }
    __shared__ float wred[8];
    const int t = threadIdx.x;
    const int b = blockIdx.x >> 6;
    const int g0 = (blockIdx.x & 63) << 4;
    const int w = t >> 6, l = t & 63;

    const float4* cb = (const float4*)(c8 + (b << 10));
    const float4 c0 = cb[2*l], c1 = cb[2*l+1], c2 = cb[128+2*l], c3 = cb[129+2*l];
    const float cm[16] = {c0.x,c0.y,c0.z,c0.w, c1.x,c1.y,c1.z,c1.w,
                          c2.x,c2.y,c2.z,c2.w, c3.x,c3.y,c3.z,c3.w};

    float s1 = 0.f, s2 = 0.f;
    for (int rr = 0; rr < 4; ++rr) {
        const int row = g0 + w*4 + rr;
        float* Arow = dout + A_OFF + (((size_t)(b*NN + row)) << 10);
        if (row < NUM_IN) {
            const float4 z = make_float4(0.f,0.f,0.f,0.f);
            ((float4*)Arow)[2*l] = z;       ((float4*)Arow)[2*l+1] = z;
            ((float4*)Arow)[128+2*l] = z;   ((float4*)Arow)[129+2*l] = z;
        } else {
            const float ri = r8[(b << 10) + row];
            const unsigned* rp = A1 + (((size_t)(b*NN + row)) << 9);
            const uint4 v0 = ((const uint4*)rp)[l];
            const uint4 v1 = ((const uint4*)rp)[64 + l];
            float e[16];
            e[0]=bflo(v0.x); e[1]=bfhi(v0.x); e[2]=bflo(v0.y); e[3]=bfhi(v0.y);
            e[4]=bflo(v0.z); e[5]=bfhi(v0.z); e[6]=bflo(v0.w); e[7]=bfhi(v0.w);
            e[8]=bflo(v1.x); e[9]=bfhi(v1.x); e[10]=bflo(v1.y); e[11]=bfhi(v1.y);
            e[12]=bflo(v1.z); e[13]=bfhi(v1.z); e[14]=bflo(v1.w); e[15]=bfhi(v1.w);
            #pragma unroll
            for (int j = 0; j < 16; ++j) {
                e[j] = e[j] * ri * cm[j];
                s1 += e[j]; s2 += e[j]*e[j];
            }
            ((float4*)Arow)[2*l]     = make_float4(e[0],e[1],e[2],e[3]);
            ((float4*)Arow)[2*l+1]   = make_float4(e[4],e[5],e[6],e[7]);
            ((float4*)Arow)[128+2*l] = make_float4(e[8],e[9],e[10],e[11]);
            ((float4*)Arow)[129+2*l] = make_float4(e[12],e[13],e[14],e[15]);
        }
    }
    s1 = wave_sum(s1); s2 = wave_sum(s2);
    if (l == 0) { wred[w] = s1; wred[4 + w] = s2; }
    __syncthreads();
    if (t == 0) {
        atomicAdd(&reds[4 + b], wred[0]+wred[1]+wred[2]+wred[3]);
        atomicAdd(&reds[8 + b], wred[4]+wred[5]+wred[6]+wred[7]);
    }
}

// ---------- K7: V = output + relu(0.02 - var) * noise ----------
__global__ __launch_bounds__(256) void vbuild_kernel(
    const float* __restrict__ outp, const float* __restrict__ noise,
    const float* __restrict__ reds, float* __restrict__ V)
{
    const int i = blockIdx.x * 256 + threadIdx.x;
    const int b = i >> 15;
    const float Mn = 1048576.f;
    const float S1 = reds[4 + b], S2 = reds[8 + b];
    const float var = (S2 - S1*S1/Mn) / (Mn - 1.f);
    const float vd = fmaxf(0.02f - var, 0.f);
    const float4 o = ((const float4*)outp)[i];
    const float4 n = ((const float4*)noise)[i];
    ((float4*)V)[i] = make_float4(o.x + vd*n.x, o.y + vd*n.y,
                                  o.z + vd*n.z, o.w + vd*n.w);
}

// ---------- K8a: split-K partials; grid 960 main + 384 pred ----------
__global__ __launch_bounds__(256) void av_part(
    const float* __restrict__ A, const float* __restrict__ V,
    float* __restrict__ P,
    const float* __restrict__ state, const float* __restrict__ w1,
    float* __restrict__ dout, int predBase)
{
    if (blockIdx.x >= 960) {
        pred_node(predBase + (int)blockIdx.x - 960, state, w1, dout);
        return;
    }
    const int bid = blockIdx.x;
    const int ks = bid & 3;
    const int rt = (bid >> 2) % 60;
    const int b  = bid / 240;
    const int r0 = NUM_IN + rt * 16;
    const int mc0 = ks << 8;
    const int t = threadIdx.x;
    const int d = t & 127, rg = t >> 7;
    const int rowb = r0 + rg*8;

    float acc[8] = {0.f,0.f,0.f,0.f,0.f,0.f,0.f,0.f};
    const float* Vb = V + ((size_t)b << 17) + ((size_t)mc0 << 7) + d;
    const float* Ab = A + (((size_t)(b*NN + rowb)) << 10) + mc0;

    #pragma unroll 4
    for (int mq = 0; mq < 64; ++mq) {
        const float v0 = Vb[(mq*4 + 0) << 7];
        const float v1 = Vb[(mq*4 + 1) << 7];
        const float v2 = Vb[(mq*4 + 2) << 7];
        const float v3 = Vb[(mq*4 + 3) << 7];
        #pragma unroll
        for (int k = 0; k < 8; ++k) {
            const float4 a = *(const float4*)(Ab + ((size_t)k << 10) + mq*4);
            acc[k] += a.x*v0 + a.y*v1 + a.z*v2 + a.w*v3;
        }
    }
    #pragma unroll
    for (int k = 0; k < 8; ++k) {
        const int ridx = rt*16 + rg*8 + k;
        P[(((size_t)(ks*NB + b)) * 960 + ridx) * 128 + d] = acc[k];
    }
}

// ---------- K8b: sum partials + softsign -> dout; env rows ----------
__global__ __launch_bounds__(256) void av_fin(
    const float* __restrict__ P, const float* __restrict__ env,
    float* __restrict__ dout)
{
    const int t = threadIdx.x;
    int bid = blockIdx.x;
    if (bid < 128) {
        const int idx = bid*256 + t;
        const int b = idx >> 13, off = idx & 8191;
        const int r = off >> 7, d = off & 127;
        dout[((size_t)(b*NN + r)) * OUT_STRIDE + d] = env[idx];
        return;
    }
    bid -= 128;
    const int idx = bid*256 + t;
    const int d = idx & 127;
    const int rd = idx >> 7;
    const int b = rd / 960;
    const int ridx = rd - b*960;
    const float s = P[idx] + P[idx + 491520] + P[idx + 2*491520] + P[idx + 3*491520];
    dout[((size_t)(b*NN + NUM_IN + ridx)) * OUT_STRIDE + d] = s / (1.f + fabsf(s));
}

extern "C" void kernel_launch(void* const* d_in, const int* in_sizes, int n_in,
                              void* d_out, int out_size, void* d_ws, size_t ws_size,
                              hipStream_t stream)
{
    (void)in_sizes; (void)n_in; (void)out_size; (void)ws_size;
    const float* state = (const float*)d_in[0];
    const float* outp  = (const float*)d_in[1];
    const float* w1    = (const float*)d_in[2];
    const float* w2    = (const float*)d_in[3];
    const float* w3    = (const float*)d_in[4];
    const float* A_ema = (const float*)d_in[5];
    const float* env   = (const float*)d_in[6];
    const float* noise = (const float*)d_in[7];
    float* dout = (float*)d_out;

    unsigned* M0  = (unsigned*)(dout + A_OFF);
    unsigned* M0T = M0 + 2097152;

    float*    Qg   = (float*)d_ws;
    float*    Kg   = Qg + 524288;
    float*    Vg   = Kg + 524288;
    unsigned* raw  = (unsigned*)(Vg + 524288);   // reused as A1 after emaT
    unsigned* A1   = raw;
    unsigned* A1T  = raw + 2097152;
    float*    Pp   = (float*)A1T;                // av partials reuse A1T
    float*    SR1  = (float*)(A1T + 2097152);
    float*    reds = SR1 + 4096;
    float*    SC1  = reds + 16;
    float*    SR2  = SC1 + 4096;
    float*    SC2  = SR2 + 4096;
    float*    RV1  = SC2 + 4096;
    float*    RV2  = RV1 + 4096;

    hipMemsetAsync(SR1, 0, (4096 + 16) * sizeof(float), stream);

    qk_kernel<<<dim3(NB*NN), dim3(256), 0, stream>>>(state, w2, w3, Qg, Kg);

    int pb = 0;
    qk2_kernel<<<dim3(4096 + 512), dim3(256), 0, stream>>>(
        Qg, Kg, raw, reds, state, w1, dout, pb);
    pb += 512;

    emaT_kernel<<<dim3(1024 + 512), dim3(256), 0, stream>>>(
        raw, A_ema, reds, M0, M0T, SR1, state, w1, dout, pb);
    pb += 512;

    // Sinkhorn call 1: 15 matvecs (r1 fused into emaT rowsums)
    mv_kernel<true ><<<dim3(1024 + 64), dim3(256), 0, stream>>>(
        M0T, SR1, SC1, state, w1, dout, pb);
    pb += 64;
    for (int k = 1; k < 15; ++k) {
        if (k & 1)
            mv_kernel<false><<<dim3(1024 + 64), dim3(256), 0, stream>>>(
                M0, SC1, RV1, state, w1, dout, pb);
        else
            mv_kernel<false><<<dim3(1024 + 64), dim3(256), 0, stream>>>(
                M0T, RV1, SC1, state, w1, dout, pb);
        pb += 64;
    }

    thresh_kernel<<<dim3(256 + 384), dim3(256), 0, stream>>>(
        M0, M0T, RV1, SC1, A1, A1T, SR2, state, w1, dout, pb);
    pb += 384;

    // Sinkhorn call 2
    mv_kernel<true ><<<dim3(1024 + 64), dim3(256), 0, stream>>>(
        A1T, SR2, SC2, state, w1, dout, pb);
    pb += 64;
    for (int k = 1; k < 15; ++k) {
        if (k & 1)
            mv_kernel<false><<<dim3(1024 + 64), dim3(256), 0, stream>>>(
                A1, SC2, RV2, state, w1, dout, pb);
        else
            mv_kernel<false><<<dim3(1024 + 64), dim3(256), 0, stream>>>(
                A1T, RV2, SC2, state, w1, dout, pb);
        pb += 64;
    }

    fin_kernel<<<dim3(256 + 384), dim3(256), 0, stream>>>(
        A1, RV2, SC2, reds, dout, state, w1, pb);
    pb += 384;

    vbuild_kernel<<<dim3(512), dim3(256), 0, stream>>>(outp, noise, reds, Vg);

    av_part<<<dim3(960 + 384), dim3(256), 0, stream>>>(
        dout + A_OFF, Vg, Pp, state, w1, dout, pb);
    pb += 384;   // == 4096

    av_fin<<<dim3(2048), dim3(256), 0, stream>>>(Pp, env, dout);
}

// Round 11
// 437.323 us; speedup vs baseline: 1.4274x; 1.0102x over previous
//
#include <hip/hip_runtime.h>
#include <math.h>

#define NB 4
#define NN 1024
#define ND 128
#define NUM_IN 64
#define F_EPS 1e-8f
#define BT_SCALE 1.8477590650225735f      // sqrt(2+sqrt(2))
#define INV_SQRT_D 0.08838834764831844f   // 1/sqrt(128)
#define BASELINE (1.0f/1025.0f)
#define OUT_STRIDE 256
#define A_OFF 1048576                     // floats: NB*NN*OUT_STRIDE

__device__ __forceinline__ float buntanh_f(float x) {
    return BT_SCALE * (0.5f * x + 0.5f * tanhf(x));
}
__device__ __forceinline__ float wave_sum(float v) {
    #pragma unroll
    for (int off = 32; off > 0; off >>= 1) v += __shfl_xor(v, off, 64);
    return v;
}
__device__ __forceinline__ float bflo(unsigned u) { return __uint_as_float(u << 16); }
__device__ __forceinline__ float bfhi(unsigned u) { return __uint_as_float(u & 0xffff0000u); }
__device__ __forceinline__ unsigned bf_rne(float f) {
    unsigned x = __float_as_uint(f);
    return (x + 0x7fffu + ((x >> 16) & 1u)) >> 16;
}
__device__ __forceinline__ unsigned bf_pack(float lo, float hi) {
    return bf_rne(lo) | (bf_rne(hi) << 16);
}

typedef float f32x4 __attribute__((ext_vector_type(4)));
__device__ __forceinline__ float4 ntload4(const float4* p) {
    f32x4 v = __builtin_nontemporal_load((const f32x4*)p);
    return make_float4(v.x, v.y, v.z, v.w);
}

// ---------- piggyback: one node's prediction = buntanh(state . w1) ----------
// run by one 256-thread block; self-contained (4KB LDS for reduction)
__device__ __forceinline__ void pred_node(
    const int node, const float* __restrict__ state,
    const float* __restrict__ w1, float* __restrict__ dout)
{
    __shared__ float4 pred_red[8][32];
    const int t = threadIdx.x;
    const int g = t >> 5, m = t & 31;
    const float4* w4 = (const float4*)(w1 + ((size_t)node << 14));
    const float* srow = state + ((size_t)node << 7);
    float4 acc = make_float4(0.f, 0.f, 0.f, 0.f);
    #pragma unroll
    for (int h = 0; h < 2; ++h) {
        float4 wv[8];
        #pragma unroll
        for (int i = 0; i < 8; ++i) wv[i] = ntload4(&w4[(h*8 + i)*256 + t]);
        #pragma unroll
        for (int i = 0; i < 8; ++i) {
            const float s = srow[(h*8 + i)*8 + g];
            acc.x += s*wv[i].x; acc.y += s*wv[i].y;
            acc.z += s*wv[i].z; acc.w += s*wv[i].w;
        }
    }
    pred_red[g][m] = acc;
    __syncthreads();
    if (t < 32) {
        float4 o = pred_red[0][t];
        #pragma unroll
        for (int gg = 1; gg < 8; ++gg) {
            const float4 r = pred_red[gg][t];
            o.x += r.x; o.y += r.y; o.z += r.z; o.w += r.w;
        }
        o.x = buntanh_f(o.x); o.y = buntanh_f(o.y);
        o.z = buntanh_f(o.z); o.w = buntanh_f(o.w);
        *(float4*)(dout + (size_t)node * OUT_STRIDE + ND + 4*t) = o;
    }
}

// ---------- K1: per-node matvecs (w2,w3) -> K, Q ----------
__global__ __launch_bounds__(256, 8) void qk_kernel(
    const float* __restrict__ state,
    const float* __restrict__ w2,
    const float* __restrict__ w3,
    float* __restrict__ Qg,
    float* __restrict__ Kg)
{
    const int blk = blockIdx.x;
    const int node = ((blk & 7) << 9) | (blk >> 3);   // XCD-chunked

    __shared__ float s_state[ND];
    __shared__ float4 red[2][8][32];

    const int t = threadIdx.x;
    if (t < 32) ((float4*)s_state)[t] =
        ((const float4*)(state + ((size_t)node << 7)))[t];
    __syncthreads();

    const int g = t >> 5, m = t & 31;

    auto do_mat = [&](const float* wbase, int q) {
        const float4* w4 = (const float4*)(wbase + ((size_t)node << 14));
        float4 wv[8];
        float4 acc = make_float4(0.f, 0.f, 0.f, 0.f);
        #pragma unroll
        for (int i = 0; i < 8; ++i) wv[i] = ntload4(&w4[i*256 + t]);
        #pragma unroll
        for (int i = 0; i < 8; ++i) {
            const float s = s_state[i*8 + g];
            acc.x += s*wv[i].x; acc.y += s*wv[i].y;
            acc.z += s*wv[i].z; acc.w += s*wv[i].w;
        }
        #pragma unroll
        for (int i = 0; i < 8; ++i) wv[i] = ntload4(&w4[(8+i)*256 + t]);
        #pragma unroll
        for (int i = 0; i < 8; ++i) {
            const float s = s_state[(8+i)*8 + g];
            acc.x += s*wv[i].x; acc.y += s*wv[i].y;
            acc.z += s*wv[i].z; acc.w += s*wv[i].w;
        }
        red[q][g][m] = acc;
    };
    do_mat(w2, 0);      // -> K
    do_mat(w3, 1);      // -> Q
    __syncthreads();

    if (t < 64) {
        const int q = t >> 5, mm = t & 31;
        float4 o = red[q][0][mm];
        #pragma unroll
        for (int gg = 1; gg < 8; ++gg) {
            const float4 r = red[q][gg][mm];
            o.x += r.x; o.y += r.y; o.z += r.z; o.w += r.w;
        }
        o.x = buntanh_f(o.x); o.y = buntanh_f(o.y);
        o.z = buntanh_f(o.z); o.w = buntanh_f(o.w);
        float* base = (q == 0) ? Kg : Qg;
        *(float4*)(base + ((size_t)node << 7) + 4*mm) = o;
    }
}

// ---------- K2: raw_A = Q K^T * inv_sqrt_d -> raw (bf16); ssq atomics ----------
// grid: 4096 main + 512 pred
__global__ __launch_bounds__(256) void qk2_kernel(
    const float* __restrict__ Qg, const float* __restrict__ Kg,
    unsigned* __restrict__ rawbf, float* __restrict__ reds,
    const float* __restrict__ state, const float* __restrict__ w1,
    float* __restrict__ dout, int predBase)
{
    if (blockIdx.x >= 4096) {
        pred_node(predBase + (int)blockIdx.x - 4096, state, w1, dout);
        return;
    }
    const int b = blockIdx.x >> 10;
    const int tile = blockIdx.x & 1023;
    const int tr = tile >> 5, tc = tile & 31;

    __shared__ float Qs[32][132];
    __shared__ float Ks[32][136];
    __shared__ float wr4[4];

    const int t = threadIdx.x;
    for (int i = t; i < 1024; i += 256) {
        const int r = i >> 5, q = i & 31;
        *(float4*)&Qs[r][q*4] = *(const float4*)(Qg + (((size_t)(b*NN + tr*32 + r)) << 7) + q*4);
        *(float4*)&Ks[r][q*4] = *(const float4*)(Kg + (((size_t)(b*NN + tc*32 + r)) << 7) + q*4);
    }
    __syncthreads();

    const int ty = t >> 4;
    const int tx = t & 15;
    float a00=0.f, a01=0.f, a10=0.f, a11=0.f;
    #pragma unroll
    for (int dq = 0; dq < 32; ++dq) {
        const float4 q0 = *(const float4*)&Qs[ty][dq*4];
        const float4 q1 = *(const float4*)&Qs[ty+16][dq*4];
        const float4 k0 = *(const float4*)&Ks[2*tx][dq*4];
        const float4 k1 = *(const float4*)&Ks[2*tx+1][dq*4];
        a00 += q0.x*k0.x + q0.y*k0.y + q0.z*k0.z + q0.w*k0.w;
        a01 += q0.x*k1.x + q0.y*k1.y + q0.z*k1.z + q0.w*k1.w;
        a10 += q1.x*k0.x + q1.y*k0.y + q1.z*k0.z + q1.w*k0.w;
        a11 += q1.x*k1.x + q1.y*k1.y + q1.z*k1.z + q1.w*k1.w;
    }
    a00 *= INV_SQRT_D; a01 *= INV_SQRT_D; a10 *= INV_SQRT_D; a11 *= INV_SQRT_D;

    unsigned* r0p = rawbf + (((size_t)(b*NN + tr*32 + ty)) << 9) + tc*16;
    unsigned* r1p = rawbf + (((size_t)(b*NN + tr*32 + ty + 16)) << 9) + tc*16;
    r0p[tx] = bf_pack(a00, a01);
    r1p[tx] = bf_pack(a10, a11);

    float ssq = a00*a00 + a01*a01 + a10*a10 + a11*a11;
    ssq = wave_sum(ssq);
    if ((t & 63) == 0) wr4[t >> 6] = ssq;
    __syncthreads();
    if (t == 0) atomicAdd(&reds[b], wr4[0]+wr4[1]+wr4[2]+wr4[3]);
}

// ---------- K3: EMA+mask+eps; write M0, M0^T (bf16); rowsum atomics ----------
// grid: 1024 main + 512 pred
__global__ __launch_bounds__(256) void emaT_kernel(
    const unsigned* __restrict__ rawbf, const float* __restrict__ A_ema,
    const float* __restrict__ reds,
    unsigned* __restrict__ M0, unsigned* __restrict__ M0T,
    float* __restrict__ SR,
    const float* __restrict__ state, const float* __restrict__ w1,
    float* __restrict__ dout, int predBase)
{
    if (blockIdx.x >= 1024) {
        pred_node(predBase + (int)blockIdx.x - 1024, state, w1, dout);
        return;
    }
    const int b = blockIdx.x >> 8;
    const int tile = blockIdx.x & 255;
    const int tr = tile >> 4, tc = tile & 15;
    const int R0 = tr << 6, C0 = tc << 6;

    __shared__ float st[64][65];
    __shared__ float s_part[64][5];

    const int t = threadIdx.x;
    const int r = t >> 2, q = t & 3;
    const int row = R0 + r;
    const float scale = rsqrtf(reds[b] * (1.0f/1048576.0f) + F_EPS);

    const unsigned* rawrow = rawbf + (((size_t)(b*NN + row)) << 9) + tc*8*4;
    const uint4 u0 = ((const uint4*)rawrow)[q*2];
    const uint4 u1 = ((const uint4*)rawrow)[q*2 + 1];
    float rv[16];
    rv[0]=bflo(u0.x); rv[1]=bfhi(u0.x); rv[2]=bflo(u0.y); rv[3]=bfhi(u0.y);
    rv[4]=bflo(u0.z); rv[5]=bfhi(u0.z); rv[6]=bflo(u0.w); rv[7]=bfhi(u0.w);
    rv[8]=bflo(u1.x); rv[9]=bfhi(u1.x); rv[10]=bflo(u1.y); rv[11]=bfhi(u1.y);
    rv[12]=bflo(u1.z); rv[13]=bfhi(u1.z); rv[14]=bflo(u1.w); rv[15]=bfhi(u1.w);

    const float* emarow = A_ema + (((size_t)(b*NN + row)) << 10) + C0 + q*16;
    float s = 0.f;
    #pragma unroll
    for (int j = 0; j < 4; ++j) {
        const float4 e = ((const float4*)emarow)[j];
        float ev[4] = {e.x, e.y, e.z, e.w};
        #pragma unroll
        for (int k = 0; k < 4; ++k) {
            const int e_idx = j*4 + k;
            const int c = C0 + q*16 + e_idx;
            float em = ev[k];
            if (row == NUM_IN && c < NUM_IN) em += 3.0f / NUM_IN;
            float v = em * 0.99f + rv[e_idx] * scale * 0.01f;
            if (row < NUM_IN) v = 0.f;
            v = fmaxf(v, 0.f) + F_EPS;
            rv[e_idx] = v;
            st[r][q*16 + e_idx] = v;
            s += v;
        }
    }
    s_part[r][q] = s;

    unsigned* m0row = M0 + (((size_t)(b*NN + row)) << 9) + tc*8*4;
    uint4 o0, o1;
    o0.x = bf_pack(rv[0],rv[1]);  o0.y = bf_pack(rv[2],rv[3]);
    o0.z = bf_pack(rv[4],rv[5]);  o0.w = bf_pack(rv[6],rv[7]);
    o1.x = bf_pack(rv[8],rv[9]);  o1.y = bf_pack(rv[10],rv[11]);
    o1.z = bf_pack(rv[12],rv[13]); o1.w = bf_pack(rv[14],rv[15]);
    ((uint4*)m0row)[q*2]     = o0;
    ((uint4*)m0row)[q*2 + 1] = o1;
    __syncthreads();

    if (t < 64) {
        const float rs = s_part[t][0] + s_part[t][1] + s_part[t][2] + s_part[t][3];
        atomicAdd(&SR[b*NN + R0 + t], rs);
    }

    const int cT = t >> 2;
    float tv[16];
    #pragma unroll
    for (int k = 0; k < 16; ++k) tv[k] = st[q*16 + k][cT];
    uint4 w0, w1v;
    w0.x = bf_pack(tv[0],tv[1]);  w0.y = bf_pack(tv[2],tv[3]);
    w0.z = bf_pack(tv[4],tv[5]);  w0.w = bf_pack(tv[6],tv[7]);
    w1v.x = bf_pack(tv[8],tv[9]);  w1v.y = bf_pack(tv[10],tv[11]);
    w1v.z = bf_pack(tv[12],tv[13]); w1v.w = bf_pack(tv[14],tv[15]);
    unsigned* mtrow = M0T + (((size_t)(b*NN + C0 + cT)) << 9) + tr*8*4;
    ((uint4*)mtrow)[q*2]     = w0;
    ((uint4*)mtrow)[q*2 + 1] = w1v;
}

// ---------- K4 x30: y = 1/(A . x); grid 256 main + 64 pred ----------
template<bool INV_IN>
__global__ __launch_bounds__(256) void mv_kernel(
    const unsigned* __restrict__ Abf, const float* __restrict__ x,
    float* __restrict__ y,
    const float* __restrict__ state, const float* __restrict__ w1,
    float* __restrict__ dout, int predBase)
{
    const int blk = blockIdx.x;
    if (blk >= 256) {
        pred_node(predBase + blk - 256, state, w1, dout);
        return;
    }
    const int lp  = ((blk & 7) << 5) | (blk >> 3);   // XCD-chunked
    const int b   = lp >> 6;
    const int r0  = (lp & 63) << 4;
    const int t = threadIdx.x;
    const int w = t >> 6, l = t & 63;

    const float4* xb = (const float4*)(x + (b << 10));
    float4 x0 = xb[2*l], x1 = xb[2*l+1], x2 = xb[128+2*l], x3 = xb[129+2*l];
    if (INV_IN) {
        x0.x=1.f/x0.x; x0.y=1.f/x0.y; x0.z=1.f/x0.z; x0.w=1.f/x0.w;
        x1.x=1.f/x1.x; x1.y=1.f/x1.y; x1.z=1.f/x1.z; x1.w=1.f/x1.w;
        x2.x=1.f/x2.x; x2.y=1.f/x2.y; x2.z=1.f/x2.z; x2.w=1.f/x2.w;
        x3.x=1.f/x3.x; x3.y=1.f/x3.y; x3.z=1.f/x3.z; x3.w=1.f/x3.w;
    }

    #pragma unroll
    for (int r = 0; r < 4; ++r) {
        const int row = r0 + (w << 2) + r;
        const unsigned* rp = Abf + (((size_t)((b << 10) + row)) << 9);
        const uint4 v0 = ((const uint4*)rp)[l];
        const uint4 v1 = ((const uint4*)rp)[64 + l];
        float a = bflo(v0.x)*x0.x + bfhi(v0.x)*x0.y
                + bflo(v0.y)*x0.z + bfhi(v0.y)*x0.w
                + bflo(v0.z)*x1.x + bfhi(v0.z)*x1.y
                + bflo(v0.w)*x1.z + bfhi(v0.w)*x1.w
                + bflo(v1.x)*x2.x + bfhi(v1.x)*x2.y
                + bflo(v1.y)*x2.z + bfhi(v1.y)*x2.w
                + bflo(v1.z)*x3.x + bfhi(v1.z)*x3.y
                + bflo(v1.w)*x3.z + bfhi(v1.w)*x3.w;
        a = wave_sum(a);
        if (l == 0) y[(b << 10) + row] = 1.0f / a;
    }
}

// ---------- K5: threshold+eps -> A1, A1^T (bf16); rowsums -> SR2 ----------
// grid 256 main + 384 pred
__global__ __launch_bounds__(256) void thresh_kernel(
    const unsigned* __restrict__ M0, const unsigned* __restrict__ M0T,
    const float* __restrict__ r8, const float* __restrict__ c8,
    unsigned* __restrict__ A1, unsigned* __restrict__ A1T,
    float* __restrict__ SR2,
    const float* __restrict__ state, const float* __restrict__ w1,
    float* __restrict__ dout, int predBase)
{
    if (blockIdx.x >= 256) {
        pred_node(predBase + (int)blockIdx.x - 256, state, w1, dout);
        return;
    }
    const int t = threadIdx.x;
    const int b = blockIdx.x >> 6;
    const int g0 = (blockIdx.x & 63) << 4;
    const int w = t >> 6, l = t & 63;
    const bool doA1 = (w < 2);
    const int wr = doA1 ? w : (w - 2);
    const unsigned* src = doA1 ? M0 : M0T;
    unsigned*       dst = doA1 ? A1 : A1T;
    const float* rowS = doA1 ? r8 : c8;
    const float* colS = doA1 ? c8 : r8;

    const float4* cb = (const float4*)(colS + (b << 10));
    const float4 c0 = cb[2*l], c1 = cb[2*l+1], c2 = cb[128+2*l], c3 = cb[129+2*l];
    const float cm[16] = {c0.x,c0.y,c0.z,c0.w, c1.x,c1.y,c1.z,c1.w,
                          c2.x,c2.y,c2.z,c2.w, c3.x,c3.y,c3.z,c3.w};

    for (int rr = 0; rr < 8; ++rr) {
        const int row = g0 + wr*8 + rr;
        const float ri = rowS[(b << 10) + row];
        const unsigned* rp = src + (((size_t)(b*NN + row)) << 9);
        const uint4 v0 = ((const uint4*)rp)[l];
        const uint4 v1 = ((const uint4*)rp)[64 + l];
        float e[16];
        e[0]=bflo(v0.x); e[1]=bfhi(v0.x); e[2]=bflo(v0.y); e[3]=bfhi(v0.y);
        e[4]=bflo(v0.z); e[5]=bfhi(v0.z); e[6]=bflo(v0.w); e[7]=bfhi(v0.w);
        e[8]=bflo(v1.x); e[9]=bfhi(v1.x); e[10]=bflo(v1.y); e[11]=bfhi(v1.y);
        e[12]=bflo(v1.z); e[13]=bfhi(v1.z); e[14]=bflo(v1.w); e[15]=bfhi(v1.w);
        float s = 0.f;
        #pragma unroll
        for (int j = 0; j < 16; ++j) {
            const float d = e[j] * ri * cm[j];
            e[j] = (d > BASELINE ? d : 0.f) + F_EPS;
            s += e[j];
        }
        uint4 o0, o1;
        o0.x = bf_pack(e[0],e[1]);  o0.y = bf_pack(e[2],e[3]);
        o0.z = bf_pack(e[4],e[5]);  o0.w = bf_pack(e[6],e[7]);
        o1.x = bf_pack(e[8],e[9]);  o1.y = bf_pack(e[10],e[11]);
        o1.z = bf_pack(e[12],e[13]); o1.w = bf_pack(e[14],e[15]);
        unsigned* op = dst + (((size_t)(b*NN + row)) << 9);
        ((uint4*)op)[l] = o0;
        ((uint4*)op)[64 + l] = o1;
        if (doA1) {
            s = wave_sum(s);
            if (l == 0) SR2[b*NN + row] = s;
        }
    }
}

// ---------- K6: final scale + mask -> A (fp32); variance partials ----------
// grid 256 main + 384 pred
__global__ __launch_bounds__(256) void fin_kernel(
    const unsigned* __restrict__ A1, const float* __restrict__ r8,
    const float* __restrict__ c8, float* __restrict__ reds,
    float* __restrict__ dout,
    const float* __restrict__ state, const float* __restrict__ w1,
    int predBase)
{
    if (blockIdx.x >= 256) {
        pred_node(predBase + (int)blockIdx.x - 256, state, w1, dout);
        return;
    }
    __shared__ float wred[8];
    const int t = threadIdx.x;
    const int b = blockIdx.x >> 6;
    const int g0 = (blockIdx.x & 63) << 4;
    const int w = t >> 6, l = t & 63;

    const float4* cb = (const float4*)(c8 + (b << 10));
    const float4 c0 = cb[2*l], c1 = cb[2*l+1], c2 = cb[128+2*l], c3 = cb[129+2*l];
    const float cm[16] = {c0.x,c0.y,c0.z,c0.w, c1.x,c1.y,c1.z,c1.w,
                          c2.x,c2.y,c2.z,c2.w, c3.x,c3.y,c3.z,c3.w};

    float s1 = 0.f, s2 = 0.f;
    for (int rr = 0; rr < 4; ++rr) {
        const int row = g0 + w*4 + rr;
        float* Arow = dout + A_OFF + (((size_t)(b*NN + row)) << 10);
        if (row < NUM_IN) {
            const float4 z = make_float4(0.f,0.f,0.f,0.f);
            ((float4*)Arow)[2*l] = z;       ((float4*)Arow)[2*l+1] = z;
            ((float4*)Arow)[128+2*l] = z;   ((float4*)Arow)[129+2*l] = z;
        } else {
            const float ri = r8[(b << 10) + row];
            const unsigned* rp = A1 + (((size_t)(b*NN + row)) << 9);
            const uint4 v0 = ((const uint4*)rp)[l];
            const uint4 v1 = ((const uint4*)rp)[64 + l];
            float e[16];
            e[0]=bflo(v0.x); e[1]=bfhi(v0.x); e[2]=bflo(v0.y); e[3]=bfhi(v0.y);
            e[4]=bflo(v0.z); e[5]=bfhi(v0.z); e[6]=bflo(v0.w); e[7]=bfhi(v0.w);
            e[8]=bflo(v1.x); e[9]=bfhi(v1.x); e[10]=bflo(v1.y); e[11]=bfhi(v1.y);
            e[12]=bflo(v1.z); e[13]=bfhi(v1.z); e[14]=bflo(v1.w); e[15]=bfhi(v1.w);
            #pragma unroll
            for (int j = 0; j < 16; ++j) {
                e[j] = e[j] * ri * cm[j];
                s1 += e[j]; s2 += e[j]*e[j];
            }
            ((float4*)Arow)[2*l]     = make_float4(e[0],e[1],e[2],e[3]);
            ((float4*)Arow)[2*l+1]   = make_float4(e[4],e[5],e[6],e[7]);
            ((float4*)Arow)[128+2*l] = make_float4(e[8],e[9],e[10],e[11]);
            ((float4*)Arow)[129+2*l] = make_float4(e[12],e[13],e[14],e[15]);
        }
    }
    s1 = wave_sum(s1); s2 = wave_sum(s2);
    if (l == 0) { wred[w] = s1; wred[4 + w] = s2; }
    __syncthreads();
    if (t == 0) {
        atomicAdd(&reds[4 + b], wred[0]+wred[1]+wred[2]+wred[3]);
        atomicAdd(&reds[8 + b], wred[4]+wred[5]+wred[6]+wred[7]);
    }
}

// ---------- K7: V = output + relu(0.02 - var) * noise ----------
__global__ __launch_bounds__(256) void vbuild_kernel(
    const float* __restrict__ outp, const float* __restrict__ noise,
    const float* __restrict__ reds, float* __restrict__ V)
{
    const int i = blockIdx.x * 256 + threadIdx.x;
    const int b = i >> 15;
    const float Mn = 1048576.f;
    const float S1 = reds[4 + b], S2 = reds[8 + b];
    const float var = (S2 - S1*S1/Mn) / (Mn - 1.f);
    const float vd = fmaxf(0.02f - var, 0.f);
    const float4 o = ((const float4*)outp)[i];
    const float4 n = ((const float4*)noise)[i];
    ((float4*)V)[i] = make_float4(o.x + vd*n.x, o.y + vd*n.y,
                                  o.z + vd*n.z, o.w + vd*n.w);
}

// ---------- K8a: split-K partials; grid 960 main + 384 pred ----------
__global__ __launch_bounds__(256) void av_part(
    const float* __restrict__ A, const float* __restrict__ V,
    float* __restrict__ P,
    const float* __restrict__ state, const float* __restrict__ w1,
    float* __restrict__ dout, int predBase)
{
    if (blockIdx.x >= 960) {
        pred_node(predBase + (int)blockIdx.x - 960, state, w1, dout);
        return;
    }
    const int bid = blockIdx.x;
    const int ks = bid & 3;
    const int rt = (bid >> 2) % 60;
    const int b  = bid / 240;
    const int r0 = NUM_IN + rt * 16;
    const int mc0 = ks << 8;
    const int t = threadIdx.x;
    const int d = t & 127, rg = t >> 7;
    const int rowb = r0 + rg*8;

    float acc[8] = {0.f,0.f,0.f,0.f,0.f,0.f,0.f,0.f};
    const float* Vb = V + ((size_t)b << 17) + ((size_t)mc0 << 7) + d;
    const float* Ab = A + (((size_t)(b*NN + rowb)) << 10) + mc0;

    #pragma unroll 4
    for (int mq = 0; mq < 64; ++mq) {
        const float v0 = Vb[(mq*4 + 0) << 7];
        const float v1 = Vb[(mq*4 + 1) << 7];
        const float v2 = Vb[(mq*4 + 2) << 7];
        const float v3 = Vb[(mq*4 + 3) << 7];
        #pragma unroll
        for (int k = 0; k < 8; ++k) {
            const float4 a = *(const float4*)(Ab + ((size_t)k << 10) + mq*4);
            acc[k] += a.x*v0 + a.y*v1 + a.z*v2 + a.w*v3;
        }
    }
    #pragma unroll
    for (int k = 0; k < 8; ++k) {
        const int ridx = rt*16 + rg*8 + k;
        P[(((size_t)(ks*NB + b)) * 960 + ridx) * 128 + d] = acc[k];
    }
}

// ---------- K8b: sum partials + softsign -> dout; env rows ----------
__global__ __launch_bounds__(256) void av_fin(
    const float* __restrict__ P, const float* __restrict__ env,
    float* __restrict__ dout)
{
    const int t = threadIdx.x;
    int bid = blockIdx.x;
    if (bid < 128) {
        const int idx = bid*256 + t;
        const int b = idx >> 13, off = idx & 8191;
        const int r = off >> 7, d = off & 127;
        dout[((size_t)(b*NN + r)) * OUT_STRIDE + d] = env[idx];
        return;
    }
    bid -= 128;
    const int idx = bid*256 + t;
    const int d = idx & 127;
    const int rd = idx >> 7;
    const int b = rd / 960;
    const int ridx = rd - b*960;
    const float s = P[idx] + P[idx + 491520] + P[idx + 2*491520] + P[idx + 3*491520];
    dout[((size_t)(b*NN + NUM_IN + ridx)) * OUT_STRIDE + d] = s / (1.f + fabsf(s));
}

extern "C" void kernel_launch(void* const* d_in, const int* in_sizes, int n_in,
                              void* d_out, int out_size, void* d_ws, size_t ws_size,
                              hipStream_t stream)
{
    (void)in_sizes; (void)n_in; (void)out_size; (void)ws_size;
    const float* state = (const float*)d_in[0];
    const float* outp  = (const float*)d_in[1];
    const float* w1    = (const float*)d_in[2];
    const float* w2    = (const float*)d_in[3];
    const float* w3    = (const float*)d_in[4];
    const float* A_ema = (const float*)d_in[5];
    const float* env   = (const float*)d_in[6];
    const float* noise = (const float*)d_in[7];
    float* dout = (float*)d_out;

    unsigned* M0  = (unsigned*)(dout + A_OFF);
    unsigned* M0T = M0 + 2097152;

    float*    Qg   = (float*)d_ws;
    float*    Kg   = Qg + 524288;
    float*    Vg   = Kg + 524288;
    unsigned* raw  = (unsigned*)(Vg + 524288);   // reused as A1 after emaT
    unsigned* A1   = raw;
    unsigned* A1T  = raw + 2097152;
    float*    Pp   = (float*)A1T;                // av partials reuse A1T
    float*    SR1  = (float*)(A1T + 2097152);
    float*    reds = SR1 + 4096;
    float*    SC1  = reds + 16;
    float*    SR2  = SC1 + 4096;
    float*    SC2  = SR2 + 4096;
    float*    RV1  = SC2 + 4096;
    float*    RV2  = RV1 + 4096;

    hipMemsetAsync(SR1, 0, (4096 + 16) * sizeof(float), stream);

    qk_kernel<<<dim3(NB*NN), dim3(256), 0, stream>>>(state, w2, w3, Qg, Kg);

    int pb = 0;
    qk2_kernel<<<dim3(4096 + 512), dim3(256), 0, stream>>>(
        Qg, Kg, raw, reds, state, w1, dout, pb);
    pb += 512;

    emaT_kernel<<<dim3(1024 + 512), dim3(256), 0, stream>>>(
        raw, A_ema, reds, M0, M0T, SR1, state, w1, dout, pb);
    pb += 512;

    // Sinkhorn call 1: 15 matvecs (r1 fused into emaT rowsums)
    mv_kernel<true ><<<dim3(256 + 64), dim3(256), 0, stream>>>(
        M0T, SR1, SC1, state, w1, dout, pb);
    pb += 64;
    for (int k = 1; k < 15; ++k) {
        if (k & 1)
            mv_kernel<false><<<dim3(256 + 64), dim3(256), 0, stream>>>(
                M0, SC1, RV1, state, w1, dout, pb);
        else
            mv_kernel<false><<<dim3(256 + 64), dim3(256), 0, stream>>>(
                M0T, RV1, SC1, state, w1, dout, pb);
        pb += 64;
    }

    thresh_kernel<<<dim3(256 + 384), dim3(256), 0, stream>>>(
        M0, M0T, RV1, SC1, A1, A1T, SR2, state, w1, dout, pb);
    pb += 384;

    // Sinkhorn call 2
    mv_kernel<true ><<<dim3(256 + 64), dim3(256), 0, stream>>>(
        A1T, SR2, SC2, state, w1, dout, pb);
    pb += 64;
    for (int k = 1; k < 15; ++k) {
        if (k & 1)
            mv_kernel<false><<<dim3(256 + 64), dim3(256), 0, stream>>>(
                A1, SC2, RV2, state, w1, dout, pb);
        else
            mv_kernel<false><<<dim3(256 + 64), dim3(256), 0, stream>>>(
                A1T, RV2, SC2, state, w1, dout, pb);
        pb += 64;
    }

    fin_kernel<<<dim3(256 + 384), dim3(256), 0, stream>>>(
        A1, RV2, SC2, reds, dout, state, w1, pb);
    pb += 384;

    vbuild_kernel<<<dim3(512), dim3(256), 0, stream>>>(outp, noise, reds, Vg);

    av_part<<<dim3(960 + 384), dim3(256), 0, stream>>>(
        dout + A_OFF, Vg, Pp, state, w1, dout, pb);
    pb += 384;   // == 4096

    av_fin<<<dim3(2048), dim3(256), 0, stream>>>(Pp, env, dout);
}